// Round 12
// baseline (947.634 us; speedup 1.0000x reference)
//
#include <hip/hip_runtime.h>
#include <stdint.h>
#include <math.h>

// Problem constants
#define D_MODEL 768
#define NTOK    4096      // B*S = 2*2048
#define SEQ     2048
#define NHEAD   12
#define HDIM    64
#define D_FF    3072
#define QKV_N   2304      // 3*D_MODEL

typedef unsigned short ushort_t;  // raw bf16 bits
typedef short  short8 __attribute__((ext_vector_type(8)));
typedef float  f32x4  __attribute__((ext_vector_type(4)));
typedef float  f32x16 __attribute__((ext_vector_type(16)));

__device__ __forceinline__ float b2f(ushort_t u) {
  union { unsigned int u; float f; } v; v.u = ((unsigned int)u) << 16; return v.f;
}
__device__ __forceinline__ ushort_t f2b(float f) {
  union { float f; unsigned int u; } v; v.f = f;
  unsigned int u = v.u;
  return (ushort_t)((u + 0x7fffu + ((u >> 16) & 1u)) >> 16);  // RNE
}
__device__ __forceinline__ unsigned cvtpk_bf16(float lo, float hi) {
  unsigned r;
  asm("v_cvt_pk_bf16_f32 %0, %1, %2" : "=v"(r) : "v"(lo), "v"(hi));
  return r;
}

// ---------------------------------------------------------------- weight transpose+cast
// [K,N] fp32 -> [N,K] bf16. blockIdx.y = layer (grid.y=4 all-layer mode, 1 per-layer).
__global__ __launch_bounds__(256) void transpose_layers(
    const float* __restrict__ qkv_w, const float* __restrict__ out_w,
    const float* __restrict__ fc1_w, const float* __restrict__ fc2_w,
    ushort_t* __restrict__ qkvT, ushort_t* __restrict__ outT,
    ushort_t* __restrict__ f1T, ushort_t* __restrict__ f2T) {
  __shared__ ushort_t tile[32][33];
  int bid = blockIdx.x;
  size_t l = blockIdx.y;
  const float* src; ushort_t* dst; int K, N, tn, tk;
  if (bid < 1728)      { src = qkv_w + l * D_MODEL * QKV_N; dst = qkvT + l * D_MODEL * QKV_N;
                         K = 768;  N = 2304; tn = bid % 72;  tk = bid / 72; }
  else if (bid < 2304) { int b = bid - 1728; src = out_w + l * D_MODEL * D_MODEL; dst = outT + l * D_MODEL * D_MODEL;
                         K = 768;  N = 768;  tn = b % 24; tk = b / 24; }
  else if (bid < 4608) { int b = bid - 2304; src = fc1_w + l * D_MODEL * D_FF; dst = f1T + l * D_MODEL * D_FF;
                         K = 768;  N = 3072; tn = b % 96; tk = b / 96; }
  else                 { int b = bid - 4608; src = fc2_w + l * D_FF * D_MODEL; dst = f2T + l * D_FF * D_MODEL;
                         K = 3072; N = 768;  tn = b % 24; tk = b / 24; }
  int n0 = tn * 32, k0 = tk * 32;
  int tx = threadIdx.x, ty = threadIdx.y;       // (32,8)
  #pragma unroll
  for (int i = 0; i < 32; i += 8)
    tile[ty + i][tx] = f2b(src[(size_t)(k0 + ty + i) * N + n0 + tx]);
  __syncthreads();
  #pragma unroll
  for (int i = 0; i < 32; i += 8)
    dst[(size_t)(n0 + ty + i) * K + k0 + tx] = tile[tx][ty + i];
}

// ---------------------------------------------------------------- layernorm
__global__ __launch_bounds__(256) void ln_kernel(const float* __restrict__ x,
                                                 const float* __restrict__ w,
                                                 const float* __restrict__ b,
                                                 ushort_t* __restrict__ out) {
  __shared__ float red[4];
  int tok = blockIdx.x, t = threadIdx.x;
  const float* xr = x + (size_t)tok * D_MODEL;
  float v0 = xr[t], v1 = xr[t + 256], v2 = xr[t + 512];
  float s = v0 + v1 + v2;
  #pragma unroll
  for (int o = 1; o < 64; o <<= 1) s += __shfl_xor(s, o, 64);
  if ((t & 63) == 0) red[t >> 6] = s;
  __syncthreads();
  float mean = (red[0] + red[1] + red[2] + red[3]) * (1.0f / 768.0f);
  __syncthreads();
  float d0 = v0 - mean, d1 = v1 - mean, d2 = v2 - mean;
  float q = d0 * d0 + d1 * d1 + d2 * d2;
  #pragma unroll
  for (int o = 1; o < 64; o <<= 1) q += __shfl_xor(q, o, 64);
  if ((t & 63) == 0) red[t >> 6] = q;
  __syncthreads();
  float var = (red[0] + red[1] + red[2] + red[3]) * (1.0f / 768.0f);
  float rs = rsqrtf(var + 1e-5f);
  ushort_t* orow = out + (size_t)tok * D_MODEL;
  orow[t]       = f2b(d0 * rs * w[t]       + b[t]);
  orow[t + 256] = f2b(d1 * rs * w[t + 256] + b[t + 256]);
  orow[t + 512] = f2b(d2 * rs * w[t + 512] + b[t + 512]);
}

// ---------------------------------------------------------------- combine + (optional) layernorm
// x = sum of 4 split-K partials + bias + resid -> xout (fp32); DO_LN: also LN -> h bf16.
template <int DO_LN>
__global__ __launch_bounds__(256) void combine_ln_kernel(
    const float* __restrict__ P, const float* __restrict__ bias,
    const float* __restrict__ resid, const float* __restrict__ w,
    const float* __restrict__ b, float* __restrict__ xout,
    ushort_t* __restrict__ h) {
  __shared__ float red[4];
  int tok = blockIdx.x, t = threadIdx.x;
  size_t ro = (size_t)tok * D_MODEL;
  const size_t PS = (size_t)NTOK * D_MODEL;
  int c0 = t, c1 = t + 256, c2 = t + 512;
  float v0 = bias[c0] + resid[ro + c0] + P[ro + c0] + P[PS + ro + c0] + P[2 * PS + ro + c0] + P[3 * PS + ro + c0];
  float v1 = bias[c1] + resid[ro + c1] + P[ro + c1] + P[PS + ro + c1] + P[2 * PS + ro + c1] + P[3 * PS + ro + c1];
  float v2 = bias[c2] + resid[ro + c2] + P[ro + c2] + P[PS + ro + c2] + P[2 * PS + ro + c2] + P[3 * PS + ro + c2];
  xout[ro + c0] = v0; xout[ro + c1] = v1; xout[ro + c2] = v2;
  if constexpr (DO_LN) {
    float s = v0 + v1 + v2;
    #pragma unroll
    for (int o = 1; o < 64; o <<= 1) s += __shfl_xor(s, o, 64);
    if ((t & 63) == 0) red[t >> 6] = s;
    __syncthreads();
    float mean = (red[0] + red[1] + red[2] + red[3]) * (1.0f / 768.0f);
    __syncthreads();
    float d0 = v0 - mean, d1 = v1 - mean, d2 = v2 - mean;
    float q = d0 * d0 + d1 * d1 + d2 * d2;
    #pragma unroll
    for (int o = 1; o < 64; o <<= 1) q += __shfl_xor(q, o, 64);
    if ((t & 63) == 0) red[t >> 6] = q;
    __syncthreads();
    float var = (red[0] + red[1] + red[2] + red[3]) * (1.0f / 768.0f);
    float rs = rsqrtf(var + 1e-5f);
    ushort_t* orow = h + ro;
    orow[c0] = f2b(d0 * rs * w[c0] + b[c0]);
    orow[c1] = f2b(d1 * rs * w[c1] + b[c1]);
    orow[c2] = f2b(d2 * rs * w[c2] + b[c2]);
  }
}

// ---------------------------------------------------------------- GEMM (MFMA bf16), 128 x TN tile
// C[M,N] = A[M,K] * BT[N,K]^T + bias. DOUBLE-BUFFERED K-loop, one barrier/iter.
// XCD-chunked block swizzle. EPI: 0 bias->bf16 | 1 bias+gelu->bf16
template <int EPI, int TN>
__global__ __launch_bounds__(256) void gemm_kernel(
    const ushort_t* __restrict__ A, const ushort_t* __restrict__ BT,
    const float* __restrict__ bias,
    ushort_t* __restrict__ Cb, int M, int N, int K) {
  constexpr int NI = 4;
  __shared__ ushort_t As[2][128 * 32];
  __shared__ ushort_t Bs[2][TN * 32];
  int t = threadIdx.x;
  int lane = t & 63, wave = t >> 6;
  // XCD-aware bijective chunk swizzle (T1)
  int gx = gridDim.x;
  int nwg = gx * gridDim.y;
  int bid0 = blockIdx.y * gx + blockIdx.x;
  int qn = nwg >> 3, rm = nwg & 7;
  int xcd = bid0 & 7, pos = bid0 >> 3;
  int wg = (xcd < rm ? xcd * (qn + 1) : rm * (qn + 1) + (xcd - rm) * qn) + pos;
  int m0 = (wg / gx) * 128, n0 = (wg % gx) * TN;
  int wm = (wave & 1) * 64;
  int wn = (wave >> 1) * 64;
  int quad = lane >> 4, l16 = lane & 15;
  int kq = quad * 8;
  int lrow = lane >> 2, lcol = (lane & 3) * 8;   // staging: 16B per lane

  auto stage = [&](int k0, int buf) {
    #pragma unroll
    for (int c = 0; c < 2; ++c) {
      int rowA = wave * 32 + c * 16 + lrow;
      const ushort_t* ga = A + (size_t)(m0 + rowA) * K + k0 + lcol;
      ushort_t* la = &As[buf][(wave * 32 + c * 16) * 32];
      __builtin_amdgcn_global_load_lds((const __attribute__((address_space(1))) void*)ga,
                                       (__attribute__((address_space(3))) void*)la, 16, 0, 0);
      const ushort_t* gb = BT + (size_t)(n0 + rowA) * K + k0 + lcol;
      ushort_t* lb = &Bs[buf][(wave * 32 + c * 16) * 32];
      __builtin_amdgcn_global_load_lds((const __attribute__((address_space(1))) void*)gb,
                                       (__attribute__((address_space(3))) void*)lb, 16, 0, 0);
    }
  };

  f32x4 acc[NI][4];
  #pragma unroll
  for (int i = 0; i < NI; ++i)
    #pragma unroll
    for (int j = 0; j < 4; ++j) acc[i][j] = (f32x4){0.f, 0.f, 0.f, 0.f};

  stage(0, 0);                      // prologue prefetch
  int nk = K / 32;
  for (int ki = 0; ki < nk; ++ki) {
    int cur = ki & 1;
    __syncthreads();                // tile ki resident; prev reads of buf[cur^1] done
    if (ki + 1 < nk) stage((ki + 1) * 32, cur ^ 1);
    short8 af[NI], bf[4];
    #pragma unroll
    for (int i = 0; i < NI; ++i)
      af[i] = *(const short8*)&As[cur][(wm + i * 16 + l16) * 32 + kq];
    #pragma unroll
    for (int j = 0; j < 4; ++j)
      bf[j] = *(const short8*)&Bs[cur][(wn + j * 16 + l16) * 32 + kq];
    #pragma unroll
    for (int i = 0; i < NI; ++i)
      #pragma unroll
      for (int j = 0; j < 4; ++j)
        acc[i][j] = __builtin_amdgcn_mfma_f32_16x16x32_bf16(af[i], bf[j], acc[i][j], 0, 0, 0);
  }

  #pragma unroll
  for (int i = 0; i < NI; ++i) {
    #pragma unroll
    for (int j = 0; j < 4; ++j) {
      int col = n0 + wn + j * 16 + l16;
      float bv = bias[col];
      #pragma unroll
      for (int r = 0; r < 4; ++r) {
        int row = m0 + wm + i * 16 + quad * 4 + r;
        float v = acc[i][j][r] + bv;
        if (EPI == 1) {
          // gelu tanh-form: v * e/(e+1), e = exp2(2.302208*(v + 0.044715 v^3))
          float u = v + 0.044715f * v * v * v;
          u = fminf(u, 30.0f);                    // avoid inf/inf
          float e = exp2f(2.302207848f * u);
          v = v * e / (e + 1.0f);
        }
        Cb[(size_t)row * N + col] = f2b(v);
      }
    }
  }
}

// ---------------------------------------------------------------- split-K GEMM (128x128 tile, fp32 partials)
// fc2 (M=4096, N=768, K=3072): split-K x4, grid (6,32,4) = 768 blocks = 3/CU
// at full 128^2 intensity. Partials -> P[z] fp32; summed in combine_ln_kernel.
__global__ __launch_bounds__(256) void gemm_splitk_kernel(
    const ushort_t* __restrict__ A, const ushort_t* __restrict__ BT,
    float* __restrict__ P, int M, int N, int K, int KS) {
  __shared__ ushort_t As[2][128 * 32];
  __shared__ ushort_t Bs[2][128 * 32];
  int t = threadIdx.x;
  int lane = t & 63, wave = t >> 6;
  int gx = gridDim.x;
  int nwg = gx * gridDim.y;              // per-slice block count (192: div by 8)
  int bid0 = blockIdx.y * gx + blockIdx.x;
  int qn = nwg >> 3, rm = nwg & 7;
  int xcd = bid0 & 7, pos = bid0 >> 3;
  int wg = (xcd < rm ? xcd * (qn + 1) : rm * (qn + 1) + (xcd - rm) * qn) + pos;
  int m0 = (wg / gx) * 128, n0 = (wg % gx) * 128;
  int kbase = blockIdx.z * KS;
  int wm = (wave & 1) * 64, wn = (wave >> 1) * 64;
  int quad = lane >> 4, l16 = lane & 15;
  int kq = quad * 8;
  int lrow = lane >> 2, lcol = (lane & 3) * 8;

  auto stage = [&](int k0, int buf) {
    #pragma unroll
    for (int c = 0; c < 2; ++c) {
      int rowA = wave * 32 + c * 16 + lrow;
      const ushort_t* ga = A + (size_t)(m0 + rowA) * K + kbase + k0 + lcol;
      ushort_t* la = &As[buf][(wave * 32 + c * 16) * 32];
      __builtin_amdgcn_global_load_lds((const __attribute__((address_space(1))) void*)ga,
                                       (__attribute__((address_space(3))) void*)la, 16, 0, 0);
      const ushort_t* gb = BT + (size_t)(n0 + rowA) * K + kbase + k0 + lcol;
      ushort_t* lb = &Bs[buf][(wave * 32 + c * 16) * 32];
      __builtin_amdgcn_global_load_lds((const __attribute__((address_space(1))) void*)gb,
                                       (__attribute__((address_space(3))) void*)lb, 16, 0, 0);
    }
  };

  f32x4 acc[4][4];
  #pragma unroll
  for (int i = 0; i < 4; ++i)
    #pragma unroll
    for (int j = 0; j < 4; ++j) acc[i][j] = (f32x4){0.f, 0.f, 0.f, 0.f};

  stage(0, 0);
  int nk = KS / 32;
  for (int ki = 0; ki < nk; ++ki) {
    int cur = ki & 1;
    __syncthreads();
    if (ki + 1 < nk) stage((ki + 1) * 32, cur ^ 1);
    short8 af[4], bf[4];
    #pragma unroll
    for (int i = 0; i < 4; ++i)
      af[i] = *(const short8*)&As[cur][(wm + i * 16 + l16) * 32 + kq];
    #pragma unroll
    for (int j = 0; j < 4; ++j)
      bf[j] = *(const short8*)&Bs[cur][(wn + j * 16 + l16) * 32 + kq];
    #pragma unroll
    for (int i = 0; i < 4; ++i)
      #pragma unroll
      for (int j = 0; j < 4; ++j)
        acc[i][j] = __builtin_amdgcn_mfma_f32_16x16x32_bf16(af[i], bf[j], acc[i][j], 0, 0, 0);
  }

  float* Pz = P + (size_t)blockIdx.z * M * N;
  #pragma unroll
  for (int i = 0; i < 4; ++i) {
    #pragma unroll
    for (int j = 0; j < 4; ++j) {
      int col = n0 + wn + j * 16 + l16;
      #pragma unroll
      for (int r = 0; r < 4; ++r) {
        int row = m0 + wm + i * 16 + quad * 4 + r;
        Pz[(size_t)row * N + col] = acc[i][j][r];
      }
    }
  }
}

// ---------------------------------------------------------------- GEMM 64x64 tile (residual epilogue)
// For the out-proj GEMM: 64x64 tile, grid 768 = 3/CU. C = A*BT^T + bias + resid -> fp32.
__global__ __launch_bounds__(256) void gemm64_kernel(
    const ushort_t* __restrict__ A, const ushort_t* __restrict__ BT,
    const float* __restrict__ bias, const float* __restrict__ resid,
    float* __restrict__ Cf, int M, int N, int K) {
  __shared__ ushort_t As[2][64 * 32];
  __shared__ ushort_t Bs[2][64 * 32];
  int t = threadIdx.x;
  int lane = t & 63, wave = t >> 6;
  int gx = gridDim.x;
  int nwg = gx * gridDim.y;
  int bid0 = blockIdx.y * gx + blockIdx.x;
  int qn = nwg >> 3, rm = nwg & 7;
  int xcd = bid0 & 7, pos = bid0 >> 3;
  int wg = (xcd < rm ? xcd * (qn + 1) : rm * (qn + 1) + (xcd - rm) * qn) + pos;
  int m0 = (wg / gx) * 64, n0 = (wg % gx) * 64;
  int wm = (wave & 1) * 32, wn = (wave >> 1) * 32;
  int quad = lane >> 4, l16 = lane & 15;
  int kq = quad * 8;
  int lrow = lane >> 2, lcol = (lane & 3) * 8;   // 4 threads/row, 16B each

  auto stage = [&](int k0, int buf) {
    int row = wave * 16 + lrow;                  // 64 rows over 4 waves
    const ushort_t* ga = A + (size_t)(m0 + row) * K + k0 + lcol;
    ushort_t* la = &As[buf][(wave * 16) * 32];
    __builtin_amdgcn_global_load_lds((const __attribute__((address_space(1))) void*)ga,
                                     (__attribute__((address_space(3))) void*)la, 16, 0, 0);
    const ushort_t* gb = BT + (size_t)(n0 + row) * K + k0 + lcol;
    ushort_t* lb = &Bs[buf][(wave * 16) * 32];
    __builtin_amdgcn_global_load_lds((const __attribute__((address_space(1))) void*)gb,
                                     (__attribute__((address_space(3))) void*)lb, 16, 0, 0);
  };

  f32x4 acc[2][2];
  #pragma unroll
  for (int i = 0; i < 2; ++i)
    #pragma unroll
    for (int j = 0; j < 2; ++j) acc[i][j] = (f32x4){0.f, 0.f, 0.f, 0.f};

  stage(0, 0);
  int nk = K / 32;
  for (int ki = 0; ki < nk; ++ki) {
    int cur = ki & 1;
    __syncthreads();
    if (ki + 1 < nk) stage((ki + 1) * 32, cur ^ 1);
    short8 af[2], bf[2];
    #pragma unroll
    for (int i = 0; i < 2; ++i)
      af[i] = *(const short8*)&As[cur][(wm + i * 16 + l16) * 32 + kq];
    #pragma unroll
    for (int j = 0; j < 2; ++j)
      bf[j] = *(const short8*)&Bs[cur][(wn + j * 16 + l16) * 32 + kq];
    #pragma unroll
    for (int i = 0; i < 2; ++i)
      #pragma unroll
      for (int j = 0; j < 2; ++j)
        acc[i][j] = __builtin_amdgcn_mfma_f32_16x16x32_bf16(af[i], bf[j], acc[i][j], 0, 0, 0);
  }

  #pragma unroll
  for (int i = 0; i < 2; ++i) {
    #pragma unroll
    for (int j = 0; j < 2; ++j) {
      int col = n0 + wn + j * 16 + l16;
      float bv = bias[col];
      #pragma unroll
      for (int r = 0; r < 4; ++r) {
        int row = m0 + wm + i * 16 + quad * 4 + r;
        float v = acc[i][j][r] + bv + resid[(size_t)row * N + col];
        Cf[(size_t)row * N + col] = v;
      }
    }
  }
}

// ---------------------------------------------------------------- attention (MFMA 32x32, 2x2 wave partition)
// qkv bf16 [NTOK, 2304]; token t, head hd: [hd*192 + (q:0|k:64|v:128) + d]
// r4/r7/r9/r11-proven structure (63.1us, VGPR 68, zero conflicts, no spill).
// r12: launch_bounds (256,3) -> (256,4). The kernel compiles to 68 VGPR, so
// the (256,3) bound was over-conservative: at cap 128 (4 waves/SIMD) no spill
// expected, and LDS 36864 x 4 = 147456 <= 160KB -> 4 blocks/CU = 16 waves/CU
// (was 12). Latency-bound kernel -> wall time ~ inverse resident waves.
// Tripwire: WRITE_SIZE > 6144 = spill = revert to (256,3).
__global__ __launch_bounds__(256, 4) void attn_kernel(const ushort_t* __restrict__ qkv,
                                                      ushort_t* __restrict__ out) {
  __shared__ __align__(16) ushort_t Ks[2][64 * 72];   // [chunk][key][d], pad 72
  __shared__ __align__(16) ushort_t Vt[2][64 * 72];   // [chunk][d][key], pad 72
  int t = threadIdx.x;
  int lane = t & 63, wave = t >> 6;
  int l31 = lane & 31, h = lane >> 5, h8 = h * 8;
  int kh = wave & 1, qh = wave >> 1;
  int kw = kh * 32;                    // wave's key window within each 64-key chunk
  int qt = blockIdx.x;
  int bh = blockIdx.y;
  int b = bh / NHEAD, hd = bh % NHEAD;
  size_t base = (size_t)b * SEQ * QKV_N + hd * 192;

  const float kscale = 0.125f * 1.44269504088896f;  // scale * log2(e)

  // Q fragments (own q-half): B-operand col = q = qh*32 + l31, elem e <-> d = 16*ks + 8*h + e
  short8 qf[4];
  {
    const ushort_t* qp = qkv + base + (size_t)(qt * 64 + qh * 32 + l31) * QKV_N + h8;
    #pragma unroll
    for (int ks = 0; ks < 4; ++ks) qf[ks] = *(const short8*)(qp + ks * 16);
  }

  // staging (256 threads stage the whole 128-key superstep into 2 chunks):
  int krow = t >> 1, kcol = (t & 1) * 32;
  int kcb = krow >> 6, krl = krow & 63;
  int kp = t & 63, vdb = (t >> 6) * 16;
  int vcb = kp >> 5, kpl = kp & 31;
  short8 kr[4], va[2], vb[2];
  auto kv_load = [&](int sbase) {
    const ushort_t* gk = qkv + base + (size_t)(sbase + krow) * QKV_N + 64 + kcol;
    #pragma unroll
    for (int i = 0; i < 4; ++i) kr[i] = *(const short8*)(gk + i * 8);
    const ushort_t* gv = qkv + base + (size_t)(sbase + 2 * kp) * QKV_N + 128 + vdb;
    va[0] = *(const short8*)gv;           va[1] = *(const short8*)(gv + 8);
    vb[0] = *(const short8*)(gv + QKV_N); vb[1] = *(const short8*)(gv + QKV_N + 8);
  };
  auto kv_write = [&]() {
    #pragma unroll
    for (int i = 0; i < 4; ++i)
      *(short8*)&Ks[kcb][krl * 72 + kcol + i * 8] = kr[i];
    unsigned* vtw = (unsigned*)&Vt[vcb][0];
    #pragma unroll
    for (int half = 0; half < 2; ++half)
      #pragma unroll
      for (int e = 0; e < 8; ++e) {
        unsigned pk = (unsigned)(unsigned short)va[half][e] |
                      ((unsigned)(unsigned short)vb[half][e] << 16);
        vtw[(vdb + half * 8 + e) * 36 + kpl] = pk;   // Vt[d][keys 2kpl, 2kpl+1]
      }
  };

  f32x16 o0, o1;                 // O[q = qh*32 + (8g+4h+r)][d = l31 / 32+l31]
  #pragma unroll
  for (int i = 0; i < 16; ++i) { o0[i] = 0.f; o1[i] = 0.f; }
  float ls = 0.f;                // partial denominator for q = qh*32 + l31

  kv_load(0);
  for (int it = 0; it < SEQ / 128; ++it) {
    kv_write();
    __syncthreads();                       // superstep staged; prev reads done
    if (it + 1 < SEQ / 128) kv_load((it + 1) * 128);

    #pragma unroll
    for (int c = 0; c < 2; ++c) {          // the two 64-key chunks
      // ---- QK^T (swapped): S^T[key, q]
      f32x16 s;
      #pragma unroll
      for (int i = 0; i < 16; ++i) s[i] = 0.f;
      __builtin_amdgcn_s_setprio(1);
      #pragma unroll
      for (int ks = 0; ks < 4; ++ks) {
        short8 kf = *(const short8*)&Ks[c][(kw + l31) * 72 + ks * 16 + h8];
        s = __builtin_amdgcn_mfma_f32_32x32x16_bf16(kf, qf[ks], s, 0, 0, 0);
      }
      __builtin_amdgcn_s_setprio(0);

      // ---- softmax numerator (fixed max = 0); reg (4g+r) <-> window-key = 8g+4h+r
      unsigned wpk[4][2];
      #pragma unroll
      for (int g = 0; g < 4; ++g) {
        float p0 = exp2f(s[4 * g + 0] * kscale), p1 = exp2f(s[4 * g + 1] * kscale);
        float p2 = exp2f(s[4 * g + 2] * kscale), p3 = exp2f(s[4 * g + 3] * kscale);
        ls += (p0 + p1) + (p2 + p3);
        wpk[g][0] = cvtpk_bf16(p0, p1);
        wpk[g][1] = cvtpk_bf16(p2, p3);
      }

      // ---- PV: O += P * V over own 32-key window; A-frag via half-wave exchange
      #pragma unroll
      for (int k4 = 0; k4 < 2; ++k4) {
        int j2 = k4 * 2;
        unsigned f[4];
        #pragma unroll
        for (int c2 = 0; c2 < 2; ++c2) {
          unsigned a  = wpk[j2][c2];        // window-keys 16k4 + 4h + {2c2, 2c2+1}
          unsigned b2 = wpk[j2 + 1][c2];    // window-keys 16k4 + 8 + 4h + {2c2, 2c2+1}
          unsigned snd = h ? a : b2;
          unsigned rcv = (unsigned)__shfl_xor((int)snd, 32, 64);
          f[c2]     = h ? rcv : a;
          f[2 + c2] = h ? b2 : rcv;
        }
        union { unsigned u[4]; short8 s8; } uc;
        uc.u[0] = f[0]; uc.u[1] = f[1]; uc.u[2] = f[2]; uc.u[3] = f[3];
        short8 ap = uc.s8;
        short8 v0 = *(const short8*)&Vt[c][(l31)      * 72 + kw + k4 * 16 + h8];
        short8 v1 = *(const short8*)&Vt[c][(32 + l31) * 72 + kw + k4 * 16 + h8];
        __builtin_amdgcn_s_setprio(1);
        o0 = __builtin_amdgcn_mfma_f32_32x32x16_bf16(ap, v0, o0, 0, 0, 0);
        o1 = __builtin_amdgcn_mfma_f32_32x32x16_bf16(ap, v1, o1, 0, 0, 0);
        __builtin_amdgcn_s_setprio(0);
      }
    }
    __syncthreads();                       // all reads done before next superstep writes
  }

  // ---- combine key-halves: wave (1,qh) -> wave (0,qh); partials additive
  float* slab = (float*)&Ks[0][0];         // 128 lanes x 33 f = 16896B (fits in Ks)
  if (kh == 1) {
    float* s = slab + (size_t)(qh * 64 + lane) * 33;
    #pragma unroll
    for (int i = 0; i < 16; ++i) { s[i] = o0[i]; s[16 + i] = o1[i]; }
    s[32] = ls;
  }
  __syncthreads();
  if (kh == 0) {
    float* s = slab + (size_t)(qh * 64 + lane) * 33;
    #pragma unroll
    for (int i = 0; i < 16; ++i) { o0[i] += s[i]; o1[i] += s[16 + i]; }
    ls += s[32];
    // fold h-partner (each lane's ls covers only own-h window rows)
    ls += __shfl_xor(ls, 32, 64);

    // epilogue: rows q = qt*64 + qh*32 + (8g+4h+r); cols d = l31 / 32+l31
    size_t ob = (size_t)(b * SEQ + qt * 64 + qh * 32) * D_MODEL + hd * HDIM;
    #pragma unroll
    for (int g = 0; g < 4; ++g) {
      #pragma unroll
      for (int r = 0; r < 4; ++r) {
        int reg = 4 * g + r;
        int qrow = 8 * g + 4 * h + r;
        float inv = 1.0f / __shfl(ls, qrow, 64);
        ushort_t* orow = out + ob + (size_t)qrow * D_MODEL;
        orow[l31]      = f2b(o0[reg] * inv);
        orow[32 + l31] = f2b(o1[reg] * inv);
      }
    }
  }
}

// ---------------------------------------------------------------- launch
extern "C" void kernel_launch(void* const* d_in, const int* in_sizes, int n_in,
                              void* d_out, int out_size, void* d_ws, size_t ws_size,
                              hipStream_t stream) {
  const float* x_in  = (const float*)d_in[0];
  const float* qkv_w = (const float*)d_in[1];
  const float* qkv_b = (const float*)d_in[2];
  const float* out_w = (const float*)d_in[3];
  const float* out_b = (const float*)d_in[4];
  const float* ln1_w = (const float*)d_in[5];
  const float* ln1_b = (const float*)d_in[6];
  const float* fc1_w = (const float*)d_in[7];
  const float* fc1_b = (const float*)d_in[8];
  const float* fc2_w = (const float*)d_in[9];
  const float* fc2_b = (const float*)d_in[10];
  const float* ln2_w = (const float*)d_in[11];
  const float* ln2_b = (const float*)d_in[12];

  char* ws = (char*)d_ws;
  size_t off = 0;
  auto alloc = [&](size_t bytes) -> void* {
    void* p = ws + off; off += (bytes + 255) & ~(size_t)255; return p;
  };
  float*    buf_x  = (float*)   alloc((size_t)NTOK * D_MODEL * 4);
  float*    buf_x2 = (float*)   alloc((size_t)NTOK * D_MODEL * 4);
  ushort_t* bigb   = (ushort_t*)alloc((size_t)NTOK * D_FF * 2);     // qkv_a / mlp_b union
  ushort_t* h_b    = (ushort_t*)alloc((size_t)NTOK * D_MODEL * 2);
  ushort_t* at_b   = (ushort_t*)alloc((size_t)NTOK * D_MODEL * 2);

  size_t off_base = off;
  size_t pl_w = ((size_t)QKV_N * D_MODEL + (size_t)D_MODEL * D_MODEL +
                 (size_t)D_FF * D_MODEL * 2) * 2;                   // bytes/layer (transposed)
  size_t splitk_bytes = (size_t)4 * NTOK * D_MODEL * 4;             // 4 fp32 partials
  bool use_splitk, all_layers;
  size_t slack = 64 << 10;
  if (ws_size >= off_base + splitk_bytes + 4 * pl_w + slack)      { use_splitk = true;  all_layers = true;  }
  else if (ws_size >= off_base + splitk_bytes + pl_w + slack)     { use_splitk = true;  all_layers = false; }
  else if (ws_size >= off_base + 4 * pl_w + slack)                { use_splitk = false; all_layers = true;  }
  else                                                            { use_splitk = false; all_layers = false; }
  float* Pbuf = use_splitk ? (float*)alloc(splitk_bytes) : nullptr;
  int nl = all_layers ? 4 : 1;
  ushort_t* qkvT = (ushort_t*)alloc((size_t)QKV_N * D_MODEL * 2 * nl);
  ushort_t* outT = (ushort_t*)alloc((size_t)D_MODEL * D_MODEL * 2 * nl);
  ushort_t* f1T  = (ushort_t*)alloc((size_t)D_FF * D_MODEL * 2 * nl);
  ushort_t* f2T  = (ushort_t*)alloc((size_t)D_MODEL * D_FF * 2 * nl);

  ushort_t* qkv_a = bigb;
  ushort_t* mlp_b = bigb;

  if (all_layers)
    transpose_layers<<<dim3(6912, 4), dim3(32, 8), 0, stream>>>(
        qkv_w, out_w, fc1_w, fc2_w, qkvT, outT, f1T, f2T);

  for (int l = 0; l < 4; ++l) {
    const float* resid_in = (l == 0) ? x_in : buf_x;
    size_t lw = all_layers ? (size_t)l : 0;
    ushort_t* qkvT_l = qkvT + lw * QKV_N * D_MODEL;
    ushort_t* outT_l = outT + lw * D_MODEL * D_MODEL;
    ushort_t* f1T_l  = f1T  + lw * D_FF * D_MODEL;
    ushort_t* f2T_l  = f2T  + lw * D_MODEL * D_FF;
    if (!all_layers)
      transpose_layers<<<dim3(6912, 1), dim3(32, 8), 0, stream>>>(
          qkv_w + (size_t)l * D_MODEL * QKV_N, out_w + (size_t)l * D_MODEL * D_MODEL,
          fc1_w + (size_t)l * D_MODEL * D_FF,  fc2_w + (size_t)l * D_FF * D_MODEL,
          qkvT_l, outT_l, f1T_l, f2T_l);
    // ln1: layer 0 always; later layers only if combine_ln didn't already produce h_b
    if (l == 0 || !use_splitk)
      ln_kernel<<<NTOK, 256, 0, stream>>>(resid_in, ln1_w + l * D_MODEL, ln1_b + l * D_MODEL, h_b);
    gemm_kernel<0, 128><<<dim3(QKV_N / 128, NTOK / 128), 256, 0, stream>>>(
        h_b, qkvT_l, qkv_b + l * QKV_N, qkv_a, NTOK, QKV_N, D_MODEL);
    attn_kernel<<<dim3(SEQ / 64, 2 * NHEAD), 256, 0, stream>>>(qkv_a, at_b);
    gemm64_kernel<<<dim3(D_MODEL / 64, NTOK / 64), 256, 0, stream>>>(
        at_b, outT_l, out_b + l * D_MODEL, resid_in, buf_x2, NTOK, D_MODEL, D_MODEL);
    ln_kernel<<<NTOK, 256, 0, stream>>>(buf_x2, ln2_w + l * D_MODEL, ln2_b + l * D_MODEL, h_b);
    gemm_kernel<1, 128><<<dim3(D_FF / 128, NTOK / 128), 256, 0, stream>>>(
        h_b, f1T_l, fc1_b + l * D_FF, mlp_b, NTOK, D_FF, D_MODEL);
    if (use_splitk) {
      gemm_splitk_kernel<<<dim3(D_MODEL / 128, NTOK / 128, 4), 256, 0, stream>>>(
          mlp_b, f2T_l, Pbuf, NTOK, D_MODEL, D_FF, D_FF / 4);
      if (l < 3)
        combine_ln_kernel<1><<<NTOK, 256, 0, stream>>>(
            Pbuf, fc2_b + l * D_MODEL, buf_x2,
            ln1_w + (l + 1) * D_MODEL, ln1_b + (l + 1) * D_MODEL, buf_x, h_b);
      else
        combine_ln_kernel<0><<<NTOK, 256, 0, stream>>>(
            Pbuf, fc2_b + 3 * D_MODEL, buf_x2, nullptr, nullptr, (float*)d_out, nullptr);
    } else {
      float* x_next = (l < 3) ? buf_x : (float*)d_out;
      gemm64_kernel<<<dim3(D_MODEL / 64, NTOK / 64), 256, 0, stream>>>(
          mlp_b, f2T_l, fc2_b + l * D_MODEL, buf_x2, x_next, NTOK, D_MODEL, D_FF);
    }
  }
  (void)in_sizes; (void)n_in; (void)out_size;
}

// Round 13
// 890.888 us; speedup vs baseline: 1.0637x; 1.0637x over previous
//
#include <hip/hip_runtime.h>
#include <stdint.h>
#include <math.h>

// Problem constants
#define D_MODEL 768
#define NTOK    4096      // B*S = 2*2048
#define SEQ     2048
#define NHEAD   12
#define HDIM    64
#define D_FF    3072
#define QKV_N   2304      // 3*D_MODEL

typedef unsigned short ushort_t;  // raw bf16 bits
typedef short  short8 __attribute__((ext_vector_type(8)));
typedef float  f32x4  __attribute__((ext_vector_type(4)));
typedef float  f32x16 __attribute__((ext_vector_type(16)));

__device__ __forceinline__ float b2f(ushort_t u) {
  union { unsigned int u; float f; } v; v.u = ((unsigned int)u) << 16; return v.f;
}
__device__ __forceinline__ ushort_t f2b(float f) {
  union { float f; unsigned int u; } v; v.f = f;
  unsigned int u = v.u;
  return (ushort_t)((u + 0x7fffu + ((u >> 16) & 1u)) >> 16);  // RNE
}
__device__ __forceinline__ unsigned cvtpk_bf16(float lo, float hi) {
  unsigned r;
  asm("v_cvt_pk_bf16_f32 %0, %1, %2" : "=v"(r) : "v"(lo), "v"(hi));
  return r;
}

// ---------------------------------------------------------------- weight transpose+cast
// [K,N] fp32 -> [N,K] bf16. blockIdx.y = layer (grid.y=4 all-layer mode, 1 per-layer).
__global__ __launch_bounds__(256) void transpose_layers(
    const float* __restrict__ qkv_w, const float* __restrict__ out_w,
    const float* __restrict__ fc1_w, const float* __restrict__ fc2_w,
    ushort_t* __restrict__ qkvT, ushort_t* __restrict__ outT,
    ushort_t* __restrict__ f1T, ushort_t* __restrict__ f2T) {
  __shared__ ushort_t tile[32][33];
  int bid = blockIdx.x;
  size_t l = blockIdx.y;
  const float* src; ushort_t* dst; int K, N, tn, tk;
  if (bid < 1728)      { src = qkv_w + l * D_MODEL * QKV_N; dst = qkvT + l * D_MODEL * QKV_N;
                         K = 768;  N = 2304; tn = bid % 72;  tk = bid / 72; }
  else if (bid < 2304) { int b = bid - 1728; src = out_w + l * D_MODEL * D_MODEL; dst = outT + l * D_MODEL * D_MODEL;
                         K = 768;  N = 768;  tn = b % 24; tk = b / 24; }
  else if (bid < 4608) { int b = bid - 2304; src = fc1_w + l * D_MODEL * D_FF; dst = f1T + l * D_MODEL * D_FF;
                         K = 768;  N = 3072; tn = b % 96; tk = b / 96; }
  else                 { int b = bid - 4608; src = fc2_w + l * D_FF * D_MODEL; dst = f2T + l * D_FF * D_MODEL;
                         K = 3072; N = 768;  tn = b % 24; tk = b / 24; }
  int n0 = tn * 32, k0 = tk * 32;
  int tx = threadIdx.x, ty = threadIdx.y;       // (32,8)
  #pragma unroll
  for (int i = 0; i < 32; i += 8)
    tile[ty + i][tx] = f2b(src[(size_t)(k0 + ty + i) * N + n0 + tx]);
  __syncthreads();
  #pragma unroll
  for (int i = 0; i < 32; i += 8)
    dst[(size_t)(n0 + ty + i) * K + k0 + tx] = tile[tx][ty + i];
}

// ---------------------------------------------------------------- layernorm
__global__ __launch_bounds__(256) void ln_kernel(const float* __restrict__ x,
                                                 const float* __restrict__ w,
                                                 const float* __restrict__ b,
                                                 ushort_t* __restrict__ out) {
  __shared__ float red[4];
  int tok = blockIdx.x, t = threadIdx.x;
  const float* xr = x + (size_t)tok * D_MODEL;
  float v0 = xr[t], v1 = xr[t + 256], v2 = xr[t + 512];
  float s = v0 + v1 + v2;
  #pragma unroll
  for (int o = 1; o < 64; o <<= 1) s += __shfl_xor(s, o, 64);
  if ((t & 63) == 0) red[t >> 6] = s;
  __syncthreads();
  float mean = (red[0] + red[1] + red[2] + red[3]) * (1.0f / 768.0f);
  __syncthreads();
  float d0 = v0 - mean, d1 = v1 - mean, d2 = v2 - mean;
  float q = d0 * d0 + d1 * d1 + d2 * d2;
  #pragma unroll
  for (int o = 1; o < 64; o <<= 1) q += __shfl_xor(q, o, 64);
  if ((t & 63) == 0) red[t >> 6] = q;
  __syncthreads();
  float var = (red[0] + red[1] + red[2] + red[3]) * (1.0f / 768.0f);
  float rs = rsqrtf(var + 1e-5f);
  ushort_t* orow = out + (size_t)tok * D_MODEL;
  orow[t]       = f2b(d0 * rs * w[t]       + b[t]);
  orow[t + 256] = f2b(d1 * rs * w[t + 256] + b[t + 256]);
  orow[t + 512] = f2b(d2 * rs * w[t + 512] + b[t + 512]);
}

// ---------------------------------------------------------------- combine + (optional) layernorm
// x = sum of 4 split-K partials + bias + resid -> xout (fp32); DO_LN: also LN -> h bf16.
template <int DO_LN>
__global__ __launch_bounds__(256) void combine_ln_kernel(
    const float* __restrict__ P, const float* __restrict__ bias,
    const float* __restrict__ resid, const float* __restrict__ w,
    const float* __restrict__ b, float* __restrict__ xout,
    ushort_t* __restrict__ h) {
  __shared__ float red[4];
  int tok = blockIdx.x, t = threadIdx.x;
  size_t ro = (size_t)tok * D_MODEL;
  const size_t PS = (size_t)NTOK * D_MODEL;
  int c0 = t, c1 = t + 256, c2 = t + 512;
  float v0 = bias[c0] + resid[ro + c0] + P[ro + c0] + P[PS + ro + c0] + P[2 * PS + ro + c0] + P[3 * PS + ro + c0];
  float v1 = bias[c1] + resid[ro + c1] + P[ro + c1] + P[PS + ro + c1] + P[2 * PS + ro + c1] + P[3 * PS + ro + c1];
  float v2 = bias[c2] + resid[ro + c2] + P[ro + c2] + P[PS + ro + c2] + P[2 * PS + ro + c2] + P[3 * PS + ro + c2];
  xout[ro + c0] = v0; xout[ro + c1] = v1; xout[ro + c2] = v2;
  if constexpr (DO_LN) {
    float s = v0 + v1 + v2;
    #pragma unroll
    for (int o = 1; o < 64; o <<= 1) s += __shfl_xor(s, o, 64);
    if ((t & 63) == 0) red[t >> 6] = s;
    __syncthreads();
    float mean = (red[0] + red[1] + red[2] + red[3]) * (1.0f / 768.0f);
    __syncthreads();
    float d0 = v0 - mean, d1 = v1 - mean, d2 = v2 - mean;
    float q = d0 * d0 + d1 * d1 + d2 * d2;
    #pragma unroll
    for (int o = 1; o < 64; o <<= 1) q += __shfl_xor(q, o, 64);
    if ((t & 63) == 0) red[t >> 6] = q;
    __syncthreads();
    float var = (red[0] + red[1] + red[2] + red[3]) * (1.0f / 768.0f);
    float rs = rsqrtf(var + 1e-5f);
    ushort_t* orow = h + ro;
    orow[c0] = f2b(d0 * rs * w[c0] + b[c0]);
    orow[c1] = f2b(d1 * rs * w[c1] + b[c1]);
    orow[c2] = f2b(d2 * rs * w[c2] + b[c2]);
  }
}

// ---------------------------------------------------------------- GEMM (MFMA bf16), 128 x TN tile
// C[M,N] = A[M,K] * BT[N,K]^T + bias. DOUBLE-BUFFERED K-loop, one barrier/iter.
// XCD-chunked block swizzle. EPI: 0 bias->bf16 | 1 bias+gelu->bf16
template <int EPI, int TN>
__global__ __launch_bounds__(256) void gemm_kernel(
    const ushort_t* __restrict__ A, const ushort_t* __restrict__ BT,
    const float* __restrict__ bias,
    ushort_t* __restrict__ Cb, int M, int N, int K) {
  constexpr int NI = 4;
  __shared__ ushort_t As[2][128 * 32];
  __shared__ ushort_t Bs[2][TN * 32];
  int t = threadIdx.x;
  int lane = t & 63, wave = t >> 6;
  // XCD-aware bijective chunk swizzle (T1)
  int gx = gridDim.x;
  int nwg = gx * gridDim.y;
  int bid0 = blockIdx.y * gx + blockIdx.x;
  int qn = nwg >> 3, rm = nwg & 7;
  int xcd = bid0 & 7, pos = bid0 >> 3;
  int wg = (xcd < rm ? xcd * (qn + 1) : rm * (qn + 1) + (xcd - rm) * qn) + pos;
  int m0 = (wg / gx) * 128, n0 = (wg % gx) * TN;
  int wm = (wave & 1) * 64;
  int wn = (wave >> 1) * 64;
  int quad = lane >> 4, l16 = lane & 15;
  int kq = quad * 8;
  int lrow = lane >> 2, lcol = (lane & 3) * 8;   // staging: 16B per lane

  auto stage = [&](int k0, int buf) {
    #pragma unroll
    for (int c = 0; c < 2; ++c) {
      int rowA = wave * 32 + c * 16 + lrow;
      const ushort_t* ga = A + (size_t)(m0 + rowA) * K + k0 + lcol;
      ushort_t* la = &As[buf][(wave * 32 + c * 16) * 32];
      __builtin_amdgcn_global_load_lds((const __attribute__((address_space(1))) void*)ga,
                                       (__attribute__((address_space(3))) void*)la, 16, 0, 0);
      const ushort_t* gb = BT + (size_t)(n0 + rowA) * K + k0 + lcol;
      ushort_t* lb = &Bs[buf][(wave * 32 + c * 16) * 32];
      __builtin_amdgcn_global_load_lds((const __attribute__((address_space(1))) void*)gb,
                                       (__attribute__((address_space(3))) void*)lb, 16, 0, 0);
    }
  };

  f32x4 acc[NI][4];
  #pragma unroll
  for (int i = 0; i < NI; ++i)
    #pragma unroll
    for (int j = 0; j < 4; ++j) acc[i][j] = (f32x4){0.f, 0.f, 0.f, 0.f};

  stage(0, 0);                      // prologue prefetch
  int nk = K / 32;
  for (int ki = 0; ki < nk; ++ki) {
    int cur = ki & 1;
    __syncthreads();                // tile ki resident; prev reads of buf[cur^1] done
    if (ki + 1 < nk) stage((ki + 1) * 32, cur ^ 1);
    short8 af[NI], bf[4];
    #pragma unroll
    for (int i = 0; i < NI; ++i)
      af[i] = *(const short8*)&As[cur][(wm + i * 16 + l16) * 32 + kq];
    #pragma unroll
    for (int j = 0; j < 4; ++j)
      bf[j] = *(const short8*)&Bs[cur][(wn + j * 16 + l16) * 32 + kq];
    #pragma unroll
    for (int i = 0; i < NI; ++i)
      #pragma unroll
      for (int j = 0; j < 4; ++j)
        acc[i][j] = __builtin_amdgcn_mfma_f32_16x16x32_bf16(af[i], bf[j], acc[i][j], 0, 0, 0);
  }

  #pragma unroll
  for (int i = 0; i < NI; ++i) {
    #pragma unroll
    for (int j = 0; j < 4; ++j) {
      int col = n0 + wn + j * 16 + l16;
      float bv = bias[col];
      #pragma unroll
      for (int r = 0; r < 4; ++r) {
        int row = m0 + wm + i * 16 + quad * 4 + r;
        float v = acc[i][j][r] + bv;
        if (EPI == 1) {
          // gelu tanh-form: v * e/(e+1), e = exp2(2.302208*(v + 0.044715 v^3))
          float u = v + 0.044715f * v * v * v;
          u = fminf(u, 30.0f);                    // avoid inf/inf
          float e = exp2f(2.302207848f * u);
          v = v * e / (e + 1.0f);
        }
        Cb[(size_t)row * N + col] = f2b(v);
      }
    }
  }
}

// ---------------------------------------------------------------- split-K GEMM (128x128 tile, fp32 partials)
// fc2 (M=4096, N=768, K=3072): split-K x4, grid (6,32,4) = 768 blocks = 3/CU
// at full 128^2 intensity. Partials -> P[z] fp32; summed in combine_ln_kernel.
__global__ __launch_bounds__(256) void gemm_splitk_kernel(
    const ushort_t* __restrict__ A, const ushort_t* __restrict__ BT,
    float* __restrict__ P, int M, int N, int K, int KS) {
  __shared__ ushort_t As[2][128 * 32];
  __shared__ ushort_t Bs[2][128 * 32];
  int t = threadIdx.x;
  int lane = t & 63, wave = t >> 6;
  int gx = gridDim.x;
  int nwg = gx * gridDim.y;              // per-slice block count (192: div by 8)
  int bid0 = blockIdx.y * gx + blockIdx.x;
  int qn = nwg >> 3, rm = nwg & 7;
  int xcd = bid0 & 7, pos = bid0 >> 3;
  int wg = (xcd < rm ? xcd * (qn + 1) : rm * (qn + 1) + (xcd - rm) * qn) + pos;
  int m0 = (wg / gx) * 128, n0 = (wg % gx) * 128;
  int kbase = blockIdx.z * KS;
  int wm = (wave & 1) * 64, wn = (wave >> 1) * 64;
  int quad = lane >> 4, l16 = lane & 15;
  int kq = quad * 8;
  int lrow = lane >> 2, lcol = (lane & 3) * 8;

  auto stage = [&](int k0, int buf) {
    #pragma unroll
    for (int c = 0; c < 2; ++c) {
      int rowA = wave * 32 + c * 16 + lrow;
      const ushort_t* ga = A + (size_t)(m0 + rowA) * K + kbase + k0 + lcol;
      ushort_t* la = &As[buf][(wave * 32 + c * 16) * 32];
      __builtin_amdgcn_global_load_lds((const __attribute__((address_space(1))) void*)ga,
                                       (__attribute__((address_space(3))) void*)la, 16, 0, 0);
      const ushort_t* gb = BT + (size_t)(n0 + rowA) * K + kbase + k0 + lcol;
      ushort_t* lb = &Bs[buf][(wave * 32 + c * 16) * 32];
      __builtin_amdgcn_global_load_lds((const __attribute__((address_space(1))) void*)gb,
                                       (__attribute__((address_space(3))) void*)lb, 16, 0, 0);
    }
  };

  f32x4 acc[4][4];
  #pragma unroll
  for (int i = 0; i < 4; ++i)
    #pragma unroll
    for (int j = 0; j < 4; ++j) acc[i][j] = (f32x4){0.f, 0.f, 0.f, 0.f};

  stage(0, 0);
  int nk = KS / 32;
  for (int ki = 0; ki < nk; ++ki) {
    int cur = ki & 1;
    __syncthreads();
    if (ki + 1 < nk) stage((ki + 1) * 32, cur ^ 1);
    short8 af[4], bf[4];
    #pragma unroll
    for (int i = 0; i < 4; ++i)
      af[i] = *(const short8*)&As[cur][(wm + i * 16 + l16) * 32 + kq];
    #pragma unroll
    for (int j = 0; j < 4; ++j)
      bf[j] = *(const short8*)&Bs[cur][(wn + j * 16 + l16) * 32 + kq];
    #pragma unroll
    for (int i = 0; i < 4; ++i)
      #pragma unroll
      for (int j = 0; j < 4; ++j)
        acc[i][j] = __builtin_amdgcn_mfma_f32_16x16x32_bf16(af[i], bf[j], acc[i][j], 0, 0, 0);
  }

  float* Pz = P + (size_t)blockIdx.z * M * N;
  #pragma unroll
  for (int i = 0; i < 4; ++i) {
    #pragma unroll
    for (int j = 0; j < 4; ++j) {
      int col = n0 + wn + j * 16 + l16;
      #pragma unroll
      for (int r = 0; r < 4; ++r) {
        int row = m0 + wm + i * 16 + quad * 4 + r;
        Pz[(size_t)row * N + col] = acc[i][j][r];
      }
    }
  }
}

// ---------------------------------------------------------------- GEMM 64x64 tile (residual epilogue)
// For the out-proj GEMM: 64x64 tile, grid 768 = 3/CU. C = A*BT^T + bias + resid -> fp32.
__global__ __launch_bounds__(256) void gemm64_kernel(
    const ushort_t* __restrict__ A, const ushort_t* __restrict__ BT,
    const float* __restrict__ bias, const float* __restrict__ resid,
    float* __restrict__ Cf, int M, int N, int K) {
  __shared__ ushort_t As[2][64 * 32];
  __shared__ ushort_t Bs[2][64 * 32];
  int t = threadIdx.x;
  int lane = t & 63, wave = t >> 6;
  int gx = gridDim.x;
  int nwg = gx * gridDim.y;
  int bid0 = blockIdx.y * gx + blockIdx.x;
  int qn = nwg >> 3, rm = nwg & 7;
  int xcd = bid0 & 7, pos = bid0 >> 3;
  int wg = (xcd < rm ? xcd * (qn + 1) : rm * (qn + 1) + (xcd - rm) * qn) + pos;
  int m0 = (wg / gx) * 64, n0 = (wg % gx) * 64;
  int wm = (wave & 1) * 32, wn = (wave >> 1) * 32;
  int quad = lane >> 4, l16 = lane & 15;
  int kq = quad * 8;
  int lrow = lane >> 2, lcol = (lane & 3) * 8;   // 4 threads/row, 16B each

  auto stage = [&](int k0, int buf) {
    int row = wave * 16 + lrow;                  // 64 rows over 4 waves
    const ushort_t* ga = A + (size_t)(m0 + row) * K + k0 + lcol;
    ushort_t* la = &As[buf][(wave * 16) * 32];
    __builtin_amdgcn_global_load_lds((const __attribute__((address_space(1))) void*)ga,
                                     (__attribute__((address_space(3))) void*)la, 16, 0, 0);
    const ushort_t* gb = BT + (size_t)(n0 + row) * K + k0 + lcol;
    ushort_t* lb = &Bs[buf][(wave * 16) * 32];
    __builtin_amdgcn_global_load_lds((const __attribute__((address_space(1))) void*)gb,
                                     (__attribute__((address_space(3))) void*)lb, 16, 0, 0);
  };

  f32x4 acc[2][2];
  #pragma unroll
  for (int i = 0; i < 2; ++i)
    #pragma unroll
    for (int j = 0; j < 2; ++j) acc[i][j] = (f32x4){0.f, 0.f, 0.f, 0.f};

  stage(0, 0);
  int nk = K / 32;
  for (int ki = 0; ki < nk; ++ki) {
    int cur = ki & 1;
    __syncthreads();
    if (ki + 1 < nk) stage((ki + 1) * 32, cur ^ 1);
    short8 af[2], bf[2];
    #pragma unroll
    for (int i = 0; i < 2; ++i)
      af[i] = *(const short8*)&As[cur][(wm + i * 16 + l16) * 32 + kq];
    #pragma unroll
    for (int j = 0; j < 2; ++j)
      bf[j] = *(const short8*)&Bs[cur][(wn + j * 16 + l16) * 32 + kq];
    #pragma unroll
    for (int i = 0; i < 2; ++i)
      #pragma unroll
      for (int j = 0; j < 2; ++j)
        acc[i][j] = __builtin_amdgcn_mfma_f32_16x16x32_bf16(af[i], bf[j], acc[i][j], 0, 0, 0);
  }

  #pragma unroll
  for (int i = 0; i < 2; ++i) {
    #pragma unroll
    for (int j = 0; j < 2; ++j) {
      int col = n0 + wn + j * 16 + l16;
      float bv = bias[col];
      #pragma unroll
      for (int r = 0; r < 4; ++r) {
        int row = m0 + wm + i * 16 + quad * 4 + r;
        float v = acc[i][j][r] + bv + resid[(size_t)row * N + col];
        Cf[(size_t)row * N + col] = v;
      }
    }
  }
}

// ---------------------------------------------------------------- attention (MFMA 32x32, 2x2 wave partition)
// qkv bf16 [NTOK, 2304]; token t, head hd: [hd*192 + (q:0|k:64|v:128) + d]
// r4/r7/r9/r11-proven structure (63.1us, VGPR 68, zero conflicts, no spill).
// (256,3) is REQUIRED: grid 768 = exactly 3 blocks/CU (grid-capped), and any
// tighter VGPR cap spills (r12: (256,4) -> WRITE 6144->8448, 63.1->66.6us).
__global__ __launch_bounds__(256, 3) void attn_kernel(const ushort_t* __restrict__ qkv,
                                                      ushort_t* __restrict__ out) {
  __shared__ __align__(16) ushort_t Ks[2][64 * 72];   // [chunk][key][d], pad 72
  __shared__ __align__(16) ushort_t Vt[2][64 * 72];   // [chunk][d][key], pad 72
  int t = threadIdx.x;
  int lane = t & 63, wave = t >> 6;
  int l31 = lane & 31, h = lane >> 5, h8 = h * 8;
  int kh = wave & 1, qh = wave >> 1;
  int kw = kh * 32;                    // wave's key window within each 64-key chunk
  int qt = blockIdx.x;
  int bh = blockIdx.y;
  int b = bh / NHEAD, hd = bh % NHEAD;
  size_t base = (size_t)b * SEQ * QKV_N + hd * 192;

  const float kscale = 0.125f * 1.44269504088896f;  // scale * log2(e)

  // Q fragments (own q-half): B-operand col = q = qh*32 + l31, elem e <-> d = 16*ks + 8*h + e
  short8 qf[4];
  {
    const ushort_t* qp = qkv + base + (size_t)(qt * 64 + qh * 32 + l31) * QKV_N + h8;
    #pragma unroll
    for (int ks = 0; ks < 4; ++ks) qf[ks] = *(const short8*)(qp + ks * 16);
  }

  // staging (256 threads stage the whole 128-key superstep into 2 chunks):
  int krow = t >> 1, kcol = (t & 1) * 32;
  int kcb = krow >> 6, krl = krow & 63;
  int kp = t & 63, vdb = (t >> 6) * 16;
  int vcb = kp >> 5, kpl = kp & 31;
  short8 kr[4], va[2], vb[2];
  auto kv_load = [&](int sbase) {
    const ushort_t* gk = qkv + base + (size_t)(sbase + krow) * QKV_N + 64 + kcol;
    #pragma unroll
    for (int i = 0; i < 4; ++i) kr[i] = *(const short8*)(gk + i * 8);
    const ushort_t* gv = qkv + base + (size_t)(sbase + 2 * kp) * QKV_N + 128 + vdb;
    va[0] = *(const short8*)gv;           va[1] = *(const short8*)(gv + 8);
    vb[0] = *(const short8*)(gv + QKV_N); vb[1] = *(const short8*)(gv + QKV_N + 8);
  };
  auto kv_write = [&]() {
    #pragma unroll
    for (int i = 0; i < 4; ++i)
      *(short8*)&Ks[kcb][krl * 72 + kcol + i * 8] = kr[i];
    unsigned* vtw = (unsigned*)&Vt[vcb][0];
    #pragma unroll
    for (int half = 0; half < 2; ++half)
      #pragma unroll
      for (int e = 0; e < 8; ++e) {
        unsigned pk = (unsigned)(unsigned short)va[half][e] |
                      ((unsigned)(unsigned short)vb[half][e] << 16);
        vtw[(vdb + half * 8 + e) * 36 + kpl] = pk;   // Vt[d][keys 2kpl, 2kpl+1]
      }
  };

  f32x16 o0, o1;                 // O[q = qh*32 + (8g+4h+r)][d = l31 / 32+l31]
  #pragma unroll
  for (int i = 0; i < 16; ++i) { o0[i] = 0.f; o1[i] = 0.f; }
  float ls = 0.f;                // partial denominator for q = qh*32 + l31

  kv_load(0);
  for (int it = 0; it < SEQ / 128; ++it) {
    kv_write();
    __syncthreads();                       // superstep staged; prev reads done
    if (it + 1 < SEQ / 128) kv_load((it + 1) * 128);

    #pragma unroll
    for (int c = 0; c < 2; ++c) {          // the two 64-key chunks
      // ---- QK^T (swapped): S^T[key, q]
      f32x16 s;
      #pragma unroll
      for (int i = 0; i < 16; ++i) s[i] = 0.f;
      __builtin_amdgcn_s_setprio(1);
      #pragma unroll
      for (int ks = 0; ks < 4; ++ks) {
        short8 kf = *(const short8*)&Ks[c][(kw + l31) * 72 + ks * 16 + h8];
        s = __builtin_amdgcn_mfma_f32_32x32x16_bf16(kf, qf[ks], s, 0, 0, 0);
      }
      __builtin_amdgcn_s_setprio(0);

      // ---- softmax numerator (fixed max = 0); reg (4g+r) <-> window-key = 8g+4h+r
      unsigned wpk[4][2];
      #pragma unroll
      for (int g = 0; g < 4; ++g) {
        float p0 = exp2f(s[4 * g + 0] * kscale), p1 = exp2f(s[4 * g + 1] * kscale);
        float p2 = exp2f(s[4 * g + 2] * kscale), p3 = exp2f(s[4 * g + 3] * kscale);
        ls += (p0 + p1) + (p2 + p3);
        wpk[g][0] = cvtpk_bf16(p0, p1);
        wpk[g][1] = cvtpk_bf16(p2, p3);
      }

      // ---- PV: O += P * V over own 32-key window; A-frag via half-wave exchange
      #pragma unroll
      for (int k4 = 0; k4 < 2; ++k4) {
        int j2 = k4 * 2;
        unsigned f[4];
        #pragma unroll
        for (int c2 = 0; c2 < 2; ++c2) {
          unsigned a  = wpk[j2][c2];        // window-keys 16k4 + 4h + {2c2, 2c2+1}
          unsigned b2 = wpk[j2 + 1][c2];    // window-keys 16k4 + 8 + 4h + {2c2, 2c2+1}
          unsigned snd = h ? a : b2;
          unsigned rcv = (unsigned)__shfl_xor((int)snd, 32, 64);
          f[c2]     = h ? rcv : a;
          f[2 + c2] = h ? b2 : rcv;
        }
        union { unsigned u[4]; short8 s8; } uc;
        uc.u[0] = f[0]; uc.u[1] = f[1]; uc.u[2] = f[2]; uc.u[3] = f[3];
        short8 ap = uc.s8;
        short8 v0 = *(const short8*)&Vt[c][(l31)      * 72 + kw + k4 * 16 + h8];
        short8 v1 = *(const short8*)&Vt[c][(32 + l31) * 72 + kw + k4 * 16 + h8];
        __builtin_amdgcn_s_setprio(1);
        o0 = __builtin_amdgcn_mfma_f32_32x32x16_bf16(ap, v0, o0, 0, 0, 0);
        o1 = __builtin_amdgcn_mfma_f32_32x32x16_bf16(ap, v1, o1, 0, 0, 0);
        __builtin_amdgcn_s_setprio(0);
      }
    }
    __syncthreads();                       // all reads done before next superstep writes
  }

  // ---- combine key-halves: wave (1,qh) -> wave (0,qh); partials additive
  float* slab = (float*)&Ks[0][0];         // 128 lanes x 33 f = 16896B (fits in Ks)
  if (kh == 1) {
    float* s = slab + (size_t)(qh * 64 + lane) * 33;
    #pragma unroll
    for (int i = 0; i < 16; ++i) { s[i] = o0[i]; s[16 + i] = o1[i]; }
    s[32] = ls;
  }
  __syncthreads();
  if (kh == 0) {
    float* s = slab + (size_t)(qh * 64 + lane) * 33;
    #pragma unroll
    for (int i = 0; i < 16; ++i) { o0[i] += s[i]; o1[i] += s[16 + i]; }
    ls += s[32];
    // fold h-partner (each lane's ls covers only own-h window rows)
    ls += __shfl_xor(ls, 32, 64);

    // epilogue: rows q = qt*64 + qh*32 + (8g+4h+r); cols d = l31 / 32+l31
    size_t ob = (size_t)(b * SEQ + qt * 64 + qh * 32) * D_MODEL + hd * HDIM;
    #pragma unroll
    for (int g = 0; g < 4; ++g) {
      #pragma unroll
      for (int r = 0; r < 4; ++r) {
        int reg = 4 * g + r;
        int qrow = 8 * g + 4 * h + r;
        float inv = 1.0f / __shfl(ls, qrow, 64);
        ushort_t* orow = out + ob + (size_t)qrow * D_MODEL;
        orow[l31]      = f2b(o0[reg] * inv);
        orow[32 + l31] = f2b(o1[reg] * inv);
      }
    }
  }
}

// ---------------------------------------------------------------- launch
extern "C" void kernel_launch(void* const* d_in, const int* in_sizes, int n_in,
                              void* d_out, int out_size, void* d_ws, size_t ws_size,
                              hipStream_t stream) {
  const float* x_in  = (const float*)d_in[0];
  const float* qkv_w = (const float*)d_in[1];
  const float* qkv_b = (const float*)d_in[2];
  const float* out_w = (const float*)d_in[3];
  const float* out_b = (const float*)d_in[4];
  const float* ln1_w = (const float*)d_in[5];
  const float* ln1_b = (const float*)d_in[6];
  const float* fc1_w = (const float*)d_in[7];
  const float* fc1_b = (const float*)d_in[8];
  const float* fc2_w = (const float*)d_in[9];
  const float* fc2_b = (const float*)d_in[10];
  const float* ln2_w = (const float*)d_in[11];
  const float* ln2_b = (const float*)d_in[12];

  char* ws = (char*)d_ws;
  size_t off = 0;
  auto alloc = [&](size_t bytes) -> void* {
    void* p = ws + off; off += (bytes + 255) & ~(size_t)255; return p;
  };
  float*    buf_x  = (float*)   alloc((size_t)NTOK * D_MODEL * 4);
  float*    buf_x2 = (float*)   alloc((size_t)NTOK * D_MODEL * 4);
  ushort_t* bigb   = (ushort_t*)alloc((size_t)NTOK * D_FF * 2);     // qkv_a / mlp_b union
  ushort_t* h_b    = (ushort_t*)alloc((size_t)NTOK * D_MODEL * 2);
  ushort_t* at_b   = (ushort_t*)alloc((size_t)NTOK * D_MODEL * 2);

  size_t off_base = off;
  size_t pl_w = ((size_t)QKV_N * D_MODEL + (size_t)D_MODEL * D_MODEL +
                 (size_t)D_FF * D_MODEL * 2) * 2;                   // bytes/layer (transposed)
  size_t splitk_bytes = (size_t)4 * NTOK * D_MODEL * 4;             // 4 fp32 partials
  bool use_splitk, all_layers;
  size_t slack = 64 << 10;
  if (ws_size >= off_base + splitk_bytes + 4 * pl_w + slack)      { use_splitk = true;  all_layers = true;  }
  else if (ws_size >= off_base + splitk_bytes + pl_w + slack)     { use_splitk = true;  all_layers = false; }
  else if (ws_size >= off_base + 4 * pl_w + slack)                { use_splitk = false; all_layers = true;  }
  else                                                            { use_splitk = false; all_layers = false; }
  float* Pbuf = use_splitk ? (float*)alloc(splitk_bytes) : nullptr;
  int nl = all_layers ? 4 : 1;
  ushort_t* qkvT = (ushort_t*)alloc((size_t)QKV_N * D_MODEL * 2 * nl);
  ushort_t* outT = (ushort_t*)alloc((size_t)D_MODEL * D_MODEL * 2 * nl);
  ushort_t* f1T  = (ushort_t*)alloc((size_t)D_FF * D_MODEL * 2 * nl);
  ushort_t* f2T  = (ushort_t*)alloc((size_t)D_MODEL * D_FF * 2 * nl);

  ushort_t* qkv_a = bigb;
  ushort_t* mlp_b = bigb;

  if (all_layers)
    transpose_layers<<<dim3(6912, 4), dim3(32, 8), 0, stream>>>(
        qkv_w, out_w, fc1_w, fc2_w, qkvT, outT, f1T, f2T);

  for (int l = 0; l < 4; ++l) {
    const float* resid_in = (l == 0) ? x_in : buf_x;
    size_t lw = all_layers ? (size_t)l : 0;
    ushort_t* qkvT_l = qkvT + lw * QKV_N * D_MODEL;
    ushort_t* outT_l = outT + lw * D_MODEL * D_MODEL;
    ushort_t* f1T_l  = f1T  + lw * D_FF * D_MODEL;
    ushort_t* f2T_l  = f2T  + lw * D_MODEL * D_FF;
    if (!all_layers)
      transpose_layers<<<dim3(6912, 1), dim3(32, 8), 0, stream>>>(
          qkv_w + (size_t)l * D_MODEL * QKV_N, out_w + (size_t)l * D_MODEL * D_MODEL,
          fc1_w + (size_t)l * D_MODEL * D_FF,  fc2_w + (size_t)l * D_FF * D_MODEL,
          qkvT_l, outT_l, f1T_l, f2T_l);
    // ln1: layer 0 always; later layers only if combine_ln didn't already produce h_b
    if (l == 0 || !use_splitk)
      ln_kernel<<<NTOK, 256, 0, stream>>>(resid_in, ln1_w + l * D_MODEL, ln1_b + l * D_MODEL, h_b);
    gemm_kernel<0, 128><<<dim3(QKV_N / 128, NTOK / 128), 256, 0, stream>>>(
        h_b, qkvT_l, qkv_b + l * QKV_N, qkv_a, NTOK, QKV_N, D_MODEL);
    attn_kernel<<<dim3(SEQ / 64, 2 * NHEAD), 256, 0, stream>>>(qkv_a, at_b);
    gemm64_kernel<<<dim3(D_MODEL / 64, NTOK / 64), 256, 0, stream>>>(
        at_b, outT_l, out_b + l * D_MODEL, resid_in, buf_x2, NTOK, D_MODEL, D_MODEL);
    ln_kernel<<<NTOK, 256, 0, stream>>>(buf_x2, ln2_w + l * D_MODEL, ln2_b + l * D_MODEL, h_b);
    gemm_kernel<1, 128><<<dim3(D_FF / 128, NTOK / 128), 256, 0, stream>>>(
        h_b, f1T_l, fc1_b + l * D_FF, mlp_b, NTOK, D_FF, D_MODEL);
    if (use_splitk) {
      gemm_splitk_kernel<<<dim3(D_MODEL / 128, NTOK / 128, 4), 256, 0, stream>>>(
          mlp_b, f2T_l, Pbuf, NTOK, D_MODEL, D_FF, D_FF / 4);
      if (l < 3)
        combine_ln_kernel<1><<<NTOK, 256, 0, stream>>>(
            Pbuf, fc2_b + l * D_MODEL, buf_x2,
            ln1_w + (l + 1) * D_MODEL, ln1_b + (l + 1) * D_MODEL, buf_x, h_b);
      else
        combine_ln_kernel<0><<<NTOK, 256, 0, stream>>>(
            Pbuf, fc2_b + 3 * D_MODEL, buf_x2, nullptr, nullptr, (float*)d_out, nullptr);
    } else {
      float* x_next = (l < 3) ? buf_x : (float*)d_out;
      gemm64_kernel<<<dim3(D_MODEL / 64, NTOK / 64), 256, 0, stream>>>(
          mlp_b, f2T_l, fc2_b + l * D_MODEL, buf_x2, x_next, NTOK, D_MODEL, D_FF);
    }
  }
  (void)in_sizes; (void)n_in; (void)out_size;
}

// Round 14
// 889.761 us; speedup vs baseline: 1.0650x; 1.0013x over previous
//
#include <hip/hip_runtime.h>
#include <stdint.h>
#include <math.h>

// Problem constants
#define D_MODEL 768
#define NTOK    4096      // B*S = 2*2048
#define SEQ     2048
#define NHEAD   12
#define HDIM    64
#define D_FF    3072
#define QKV_N   2304      // 3*D_MODEL

typedef unsigned short ushort_t;  // raw bf16 bits
typedef short  short8 __attribute__((ext_vector_type(8)));
typedef float  f32x4  __attribute__((ext_vector_type(4)));
typedef float  f32x16 __attribute__((ext_vector_type(16)));

__device__ __forceinline__ float b2f(ushort_t u) {
  union { unsigned int u; float f; } v; v.u = ((unsigned int)u) << 16; return v.f;
}
__device__ __forceinline__ ushort_t f2b(float f) {
  union { float f; unsigned int u; } v; v.f = f;
  unsigned int u = v.u;
  return (ushort_t)((u + 0x7fffu + ((u >> 16) & 1u)) >> 16);  // RNE
}
__device__ __forceinline__ unsigned cvtpk_bf16(float lo, float hi) {
  unsigned r;
  asm("v_cvt_pk_bf16_f32 %0, %1, %2" : "=v"(r) : "v"(lo), "v"(hi));
  return r;
}

// ---------------------------------------------------------------- weight transpose+cast
// [K,N] fp32 -> [N,K] bf16. blockIdx.y = layer (grid.y=4 all-layer mode, 1 per-layer).
__global__ __launch_bounds__(256) void transpose_layers(
    const float* __restrict__ qkv_w, const float* __restrict__ out_w,
    const float* __restrict__ fc1_w, const float* __restrict__ fc2_w,
    ushort_t* __restrict__ qkvT, ushort_t* __restrict__ outT,
    ushort_t* __restrict__ f1T, ushort_t* __restrict__ f2T) {
  __shared__ ushort_t tile[32][33];
  int bid = blockIdx.x;
  size_t l = blockIdx.y;
  const float* src; ushort_t* dst; int K, N, tn, tk;
  if (bid < 1728)      { src = qkv_w + l * D_MODEL * QKV_N; dst = qkvT + l * D_MODEL * QKV_N;
                         K = 768;  N = 2304; tn = bid % 72;  tk = bid / 72; }
  else if (bid < 2304) { int b = bid - 1728; src = out_w + l * D_MODEL * D_MODEL; dst = outT + l * D_MODEL * D_MODEL;
                         K = 768;  N = 768;  tn = b % 24; tk = b / 24; }
  else if (bid < 4608) { int b = bid - 2304; src = fc1_w + l * D_MODEL * D_FF; dst = f1T + l * D_MODEL * D_FF;
                         K = 768;  N = 3072; tn = b % 96; tk = b / 96; }
  else                 { int b = bid - 4608; src = fc2_w + l * D_FF * D_MODEL; dst = f2T + l * D_FF * D_MODEL;
                         K = 3072; N = 768;  tn = b % 24; tk = b / 24; }
  int n0 = tn * 32, k0 = tk * 32;
  int tx = threadIdx.x, ty = threadIdx.y;       // (32,8)
  #pragma unroll
  for (int i = 0; i < 32; i += 8)
    tile[ty + i][tx] = f2b(src[(size_t)(k0 + ty + i) * N + n0 + tx]);
  __syncthreads();
  #pragma unroll
  for (int i = 0; i < 32; i += 8)
    dst[(size_t)(n0 + ty + i) * K + k0 + tx] = tile[tx][ty + i];
}

// ---------------------------------------------------------------- layernorm
__global__ __launch_bounds__(256) void ln_kernel(const float* __restrict__ x,
                                                 const float* __restrict__ w,
                                                 const float* __restrict__ b,
                                                 ushort_t* __restrict__ out) {
  __shared__ float red[4];
  int tok = blockIdx.x, t = threadIdx.x;
  const float* xr = x + (size_t)tok * D_MODEL;
  float v0 = xr[t], v1 = xr[t + 256], v2 = xr[t + 512];
  float s = v0 + v1 + v2;
  #pragma unroll
  for (int o = 1; o < 64; o <<= 1) s += __shfl_xor(s, o, 64);
  if ((t & 63) == 0) red[t >> 6] = s;
  __syncthreads();
  float mean = (red[0] + red[1] + red[2] + red[3]) * (1.0f / 768.0f);
  __syncthreads();
  float d0 = v0 - mean, d1 = v1 - mean, d2 = v2 - mean;
  float q = d0 * d0 + d1 * d1 + d2 * d2;
  #pragma unroll
  for (int o = 1; o < 64; o <<= 1) q += __shfl_xor(q, o, 64);
  if ((t & 63) == 0) red[t >> 6] = q;
  __syncthreads();
  float var = (red[0] + red[1] + red[2] + red[3]) * (1.0f / 768.0f);
  float rs = rsqrtf(var + 1e-5f);
  ushort_t* orow = out + (size_t)tok * D_MODEL;
  orow[t]       = f2b(d0 * rs * w[t]       + b[t]);
  orow[t + 256] = f2b(d1 * rs * w[t + 256] + b[t + 256]);
  orow[t + 512] = f2b(d2 * rs * w[t + 512] + b[t + 512]);
}

// ---------------------------------------------------------------- combine + (optional) layernorm
// x = sum of 4 split-K partials + bias + resid -> xout (fp32); DO_LN: also LN -> h bf16.
template <int DO_LN>
__global__ __launch_bounds__(256) void combine_ln_kernel(
    const float* __restrict__ P, const float* __restrict__ bias,
    const float* __restrict__ resid, const float* __restrict__ w,
    const float* __restrict__ b, float* __restrict__ xout,
    ushort_t* __restrict__ h) {
  __shared__ float red[4];
  int tok = blockIdx.x, t = threadIdx.x;
  size_t ro = (size_t)tok * D_MODEL;
  const size_t PS = (size_t)NTOK * D_MODEL;
  int c0 = t, c1 = t + 256, c2 = t + 512;
  float v0 = bias[c0] + resid[ro + c0] + P[ro + c0] + P[PS + ro + c0] + P[2 * PS + ro + c0] + P[3 * PS + ro + c0];
  float v1 = bias[c1] + resid[ro + c1] + P[ro + c1] + P[PS + ro + c1] + P[2 * PS + ro + c1] + P[3 * PS + ro + c1];
  float v2 = bias[c2] + resid[ro + c2] + P[ro + c2] + P[PS + ro + c2] + P[2 * PS + ro + c2] + P[3 * PS + ro + c2];
  xout[ro + c0] = v0; xout[ro + c1] = v1; xout[ro + c2] = v2;
  if constexpr (DO_LN) {
    float s = v0 + v1 + v2;
    #pragma unroll
    for (int o = 1; o < 64; o <<= 1) s += __shfl_xor(s, o, 64);
    if ((t & 63) == 0) red[t >> 6] = s;
    __syncthreads();
    float mean = (red[0] + red[1] + red[2] + red[3]) * (1.0f / 768.0f);
    __syncthreads();
    float d0 = v0 - mean, d1 = v1 - mean, d2 = v2 - mean;
    float q = d0 * d0 + d1 * d1 + d2 * d2;
    #pragma unroll
    for (int o = 1; o < 64; o <<= 1) q += __shfl_xor(q, o, 64);
    if ((t & 63) == 0) red[t >> 6] = q;
    __syncthreads();
    float var = (red[0] + red[1] + red[2] + red[3]) * (1.0f / 768.0f);
    float rs = rsqrtf(var + 1e-5f);
    ushort_t* orow = h + ro;
    orow[c0] = f2b(d0 * rs * w[c0] + b[c0]);
    orow[c1] = f2b(d1 * rs * w[c1] + b[c1]);
    orow[c2] = f2b(d2 * rs * w[c2] + b[c2]);
  }
}

// ---------------------------------------------------------------- GEMM (MFMA bf16), 128 x TN tile
// C[M,N] = A[M,K] * BT[N,K]^T + bias. DOUBLE-BUFFERED K-loop, one barrier/iter.
// XCD-chunked block swizzle. EPI: 0 bias->bf16 | 1 bias+gelu->bf16
// TN=96 (r14, for qkv N=2304): grid 24x32 = 768 blocks = exactly 3/CU (was
// 18x32 = 2.25/CU with TN=128 -> 25% TLP wasted). Wave = 64x48 (4x3 frags);
// B staged in 1.5 passes (rows 0-63 by all waves, 64-95 by waves 0-1),
// same wave-uniform-dest global_load_lds pattern.
template <int EPI, int TN>
__global__ __launch_bounds__(256) void gemm_kernel(
    const ushort_t* __restrict__ A, const ushort_t* __restrict__ BT,
    const float* __restrict__ bias,
    ushort_t* __restrict__ Cb, int M, int N, int K) {
  constexpr int NI = 4;
  constexpr int NJ = (TN == 96) ? 3 : 4;
  __shared__ ushort_t As[2][128 * 32];
  __shared__ ushort_t Bs[2][TN * 32];
  int t = threadIdx.x;
  int lane = t & 63, wave = t >> 6;
  // XCD-aware bijective chunk swizzle (T1)
  int gx = gridDim.x;
  int nwg = gx * gridDim.y;
  int bid0 = blockIdx.y * gx + blockIdx.x;
  int qn = nwg >> 3, rm = nwg & 7;
  int xcd = bid0 & 7, pos = bid0 >> 3;
  int wg = (xcd < rm ? xcd * (qn + 1) : rm * (qn + 1) + (xcd - rm) * qn) + pos;
  int m0 = (wg / gx) * 128, n0 = (wg % gx) * TN;
  int wm = (wave & 1) * 64;
  int wn = (wave >> 1) * (TN / 2);
  int quad = lane >> 4, l16 = lane & 15;
  int kq = quad * 8;
  int lrow = lane >> 2, lcol = (lane & 3) * 8;   // staging: 16B per lane

  auto gload = [&](const ushort_t* g, ushort_t* l) {
    __builtin_amdgcn_global_load_lds((const __attribute__((address_space(1))) void*)g,
                                     (__attribute__((address_space(3))) void*)l, 16, 0, 0);
  };

  auto stage = [&](int k0, int buf) {
    #pragma unroll
    for (int c = 0; c < 2; ++c) {
      int rowA = wave * 32 + c * 16 + lrow;
      gload(A + (size_t)(m0 + rowA) * K + k0 + lcol, &As[buf][(wave * 32 + c * 16) * 32]);
      if (TN == 128)
        gload(BT + (size_t)(n0 + rowA) * K + k0 + lcol, &Bs[buf][(wave * 32 + c * 16) * 32]);
    }
    if (TN == 96) {
      int rowB = wave * 16 + lrow;                 // rows 0..63: all 4 waves
      gload(BT + (size_t)(n0 + rowB) * K + k0 + lcol, &Bs[buf][(wave * 16) * 32]);
      if (wave < 2) {                              // rows 64..95: waves 0,1
        int rowB2 = 64 + wave * 16 + lrow;
        gload(BT + (size_t)(n0 + rowB2) * K + k0 + lcol, &Bs[buf][(64 + wave * 16) * 32]);
      }
    }
  };

  f32x4 acc[NI][NJ];
  #pragma unroll
  for (int i = 0; i < NI; ++i)
    #pragma unroll
    for (int j = 0; j < NJ; ++j) acc[i][j] = (f32x4){0.f, 0.f, 0.f, 0.f};

  stage(0, 0);                      // prologue prefetch
  int nk = K / 32;
  for (int ki = 0; ki < nk; ++ki) {
    int cur = ki & 1;
    __syncthreads();                // tile ki resident; prev reads of buf[cur^1] done
    if (ki + 1 < nk) stage((ki + 1) * 32, cur ^ 1);
    short8 af[NI], bf[NJ];
    #pragma unroll
    for (int i = 0; i < NI; ++i)
      af[i] = *(const short8*)&As[cur][(wm + i * 16 + l16) * 32 + kq];
    #pragma unroll
    for (int j = 0; j < NJ; ++j)
      bf[j] = *(const short8*)&Bs[cur][(wn + j * 16 + l16) * 32 + kq];
    #pragma unroll
    for (int i = 0; i < NI; ++i)
      #pragma unroll
      for (int j = 0; j < NJ; ++j)
        acc[i][j] = __builtin_amdgcn_mfma_f32_16x16x32_bf16(af[i], bf[j], acc[i][j], 0, 0, 0);
  }

  #pragma unroll
  for (int i = 0; i < NI; ++i) {
    #pragma unroll
    for (int j = 0; j < NJ; ++j) {
      int col = n0 + wn + j * 16 + l16;
      float bv = bias[col];
      #pragma unroll
      for (int r = 0; r < 4; ++r) {
        int row = m0 + wm + i * 16 + quad * 4 + r;
        float v = acc[i][j][r] + bv;
        if (EPI == 1) {
          // gelu tanh-form: v * e/(e+1), e = exp2(2.302208*(v + 0.044715 v^3))
          float u = v + 0.044715f * v * v * v;
          u = fminf(u, 30.0f);                    // avoid inf/inf
          float e = exp2f(2.302207848f * u);
          v = v * e / (e + 1.0f);
        }
        Cb[(size_t)row * N + col] = f2b(v);
      }
    }
  }
}

// ---------------------------------------------------------------- split-K GEMM (128x128 tile, fp32 partials)
// fc2 (M=4096, N=768, K=3072): split-K x4, grid (6,32,4) = 768 blocks = 3/CU
// at full 128^2 intensity. Partials -> P[z] fp32; summed in combine_ln_kernel.
__global__ __launch_bounds__(256) void gemm_splitk_kernel(
    const ushort_t* __restrict__ A, const ushort_t* __restrict__ BT,
    float* __restrict__ P, int M, int N, int K, int KS) {
  __shared__ ushort_t As[2][128 * 32];
  __shared__ ushort_t Bs[2][128 * 32];
  int t = threadIdx.x;
  int lane = t & 63, wave = t >> 6;
  int gx = gridDim.x;
  int nwg = gx * gridDim.y;              // per-slice block count (192: div by 8)
  int bid0 = blockIdx.y * gx + blockIdx.x;
  int qn = nwg >> 3, rm = nwg & 7;
  int xcd = bid0 & 7, pos = bid0 >> 3;
  int wg = (xcd < rm ? xcd * (qn + 1) : rm * (qn + 1) + (xcd - rm) * qn) + pos;
  int m0 = (wg / gx) * 128, n0 = (wg % gx) * 128;
  int kbase = blockIdx.z * KS;
  int wm = (wave & 1) * 64, wn = (wave >> 1) * 64;
  int quad = lane >> 4, l16 = lane & 15;
  int kq = quad * 8;
  int lrow = lane >> 2, lcol = (lane & 3) * 8;

  auto stage = [&](int k0, int buf) {
    #pragma unroll
    for (int c = 0; c < 2; ++c) {
      int rowA = wave * 32 + c * 16 + lrow;
      const ushort_t* ga = A + (size_t)(m0 + rowA) * K + kbase + k0 + lcol;
      ushort_t* la = &As[buf][(wave * 32 + c * 16) * 32];
      __builtin_amdgcn_global_load_lds((const __attribute__((address_space(1))) void*)ga,
                                       (__attribute__((address_space(3))) void*)la, 16, 0, 0);
      const ushort_t* gb = BT + (size_t)(n0 + rowA) * K + kbase + k0 + lcol;
      ushort_t* lb = &Bs[buf][(wave * 32 + c * 16) * 32];
      __builtin_amdgcn_global_load_lds((const __attribute__((address_space(1))) void*)gb,
                                       (__attribute__((address_space(3))) void*)lb, 16, 0, 0);
    }
  };

  f32x4 acc[4][4];
  #pragma unroll
  for (int i = 0; i < 4; ++i)
    #pragma unroll
    for (int j = 0; j < 4; ++j) acc[i][j] = (f32x4){0.f, 0.f, 0.f, 0.f};

  stage(0, 0);
  int nk = KS / 32;
  for (int ki = 0; ki < nk; ++ki) {
    int cur = ki & 1;
    __syncthreads();
    if (ki + 1 < nk) stage((ki + 1) * 32, cur ^ 1);
    short8 af[4], bf[4];
    #pragma unroll
    for (int i = 0; i < 4; ++i)
      af[i] = *(const short8*)&As[cur][(wm + i * 16 + l16) * 32 + kq];
    #pragma unroll
    for (int j = 0; j < 4; ++j)
      bf[j] = *(const short8*)&Bs[cur][(wn + j * 16 + l16) * 32 + kq];
    #pragma unroll
    for (int i = 0; i < 4; ++i)
      #pragma unroll
      for (int j = 0; j < 4; ++j)
        acc[i][j] = __builtin_amdgcn_mfma_f32_16x16x32_bf16(af[i], bf[j], acc[i][j], 0, 0, 0);
  }

  float* Pz = P + (size_t)blockIdx.z * M * N;
  #pragma unroll
  for (int i = 0; i < 4; ++i) {
    #pragma unroll
    for (int j = 0; j < 4; ++j) {
      int col = n0 + wn + j * 16 + l16;
      #pragma unroll
      for (int r = 0; r < 4; ++r) {
        int row = m0 + wm + i * 16 + quad * 4 + r;
        Pz[(size_t)row * N + col] = acc[i][j][r];
      }
    }
  }
}

// ---------------------------------------------------------------- GEMM 64x64 tile (residual epilogue)
// For the out-proj GEMM: 64x64 tile, grid 768 = 3/CU. C = A*BT^T + bias + resid -> fp32.
__global__ __launch_bounds__(256) void gemm64_kernel(
    const ushort_t* __restrict__ A, const ushort_t* __restrict__ BT,
    const float* __restrict__ bias, const float* __restrict__ resid,
    float* __restrict__ Cf, int M, int N, int K) {
  __shared__ ushort_t As[2][64 * 32];
  __shared__ ushort_t Bs[2][64 * 32];
  int t = threadIdx.x;
  int lane = t & 63, wave = t >> 6;
  int gx = gridDim.x;
  int nwg = gx * gridDim.y;
  int bid0 = blockIdx.y * gx + blockIdx.x;
  int qn = nwg >> 3, rm = nwg & 7;
  int xcd = bid0 & 7, pos = bid0 >> 3;
  int wg = (xcd < rm ? xcd * (qn + 1) : rm * (qn + 1) + (xcd - rm) * qn) + pos;
  int m0 = (wg / gx) * 64, n0 = (wg % gx) * 64;
  int wm = (wave & 1) * 32, wn = (wave >> 1) * 32;
  int quad = lane >> 4, l16 = lane & 15;
  int kq = quad * 8;
  int lrow = lane >> 2, lcol = (lane & 3) * 8;   // 4 threads/row, 16B each

  auto stage = [&](int k0, int buf) {
    int row = wave * 16 + lrow;                  // 64 rows over 4 waves
    const ushort_t* ga = A + (size_t)(m0 + row) * K + k0 + lcol;
    ushort_t* la = &As[buf][(wave * 16) * 32];
    __builtin_amdgcn_global_load_lds((const __attribute__((address_space(1))) void*)ga,
                                     (__attribute__((address_space(3))) void*)la, 16, 0, 0);
    const ushort_t* gb = BT + (size_t)(n0 + row) * K + k0 + lcol;
    ushort_t* lb = &Bs[buf][(wave * 16) * 32];
    __builtin_amdgcn_global_load_lds((const __attribute__((address_space(1))) void*)gb,
                                     (__attribute__((address_space(3))) void*)lb, 16, 0, 0);
  };

  f32x4 acc[2][2];
  #pragma unroll
  for (int i = 0; i < 2; ++i)
    #pragma unroll
    for (int j = 0; j < 2; ++j) acc[i][j] = (f32x4){0.f, 0.f, 0.f, 0.f};

  stage(0, 0);
  int nk = K / 32;
  for (int ki = 0; ki < nk; ++ki) {
    int cur = ki & 1;
    __syncthreads();
    if (ki + 1 < nk) stage((ki + 1) * 32, cur ^ 1);
    short8 af[2], bf[2];
    #pragma unroll
    for (int i = 0; i < 2; ++i)
      af[i] = *(const short8*)&As[cur][(wm + i * 16 + l16) * 32 + kq];
    #pragma unroll
    for (int j = 0; j < 2; ++j)
      bf[j] = *(const short8*)&Bs[cur][(wn + j * 16 + l16) * 32 + kq];
    #pragma unroll
    for (int i = 0; i < 2; ++i)
      #pragma unroll
      for (int j = 0; j < 2; ++j)
        acc[i][j] = __builtin_amdgcn_mfma_f32_16x16x32_bf16(af[i], bf[j], acc[i][j], 0, 0, 0);
  }

  #pragma unroll
  for (int i = 0; i < 2; ++i) {
    #pragma unroll
    for (int j = 0; j < 2; ++j) {
      int col = n0 + wn + j * 16 + l16;
      float bv = bias[col];
      #pragma unroll
      for (int r = 0; r < 4; ++r) {
        int row = m0 + wm + i * 16 + quad * 4 + r;
        float v = acc[i][j][r] + bv + resid[(size_t)row * N + col];
        Cf[(size_t)row * N + col] = v;
      }
    }
  }
}

// ---------------------------------------------------------------- attention (MFMA 32x32, 2x2 wave partition)
// qkv bf16 [NTOK, 2304]; token t, head hd: [hd*192 + (q:0|k:64|v:128) + d]
// r4/r7/r9/r11/r13-proven structure (63.0us, VGPR 68, zero conflicts, no spill).
// (256,3) is REQUIRED: grid 768 = exactly 3 blocks/CU (grid-capped), and any
// tighter VGPR cap spills (r12: (256,4) -> WRITE 6144->8448, 63.1->66.6us).
__global__ __launch_bounds__(256, 3) void attn_kernel(const ushort_t* __restrict__ qkv,
                                                      ushort_t* __restrict__ out) {
  __shared__ __align__(16) ushort_t Ks[2][64 * 72];   // [chunk][key][d], pad 72
  __shared__ __align__(16) ushort_t Vt[2][64 * 72];   // [chunk][d][key], pad 72
  int t = threadIdx.x;
  int lane = t & 63, wave = t >> 6;
  int l31 = lane & 31, h = lane >> 5, h8 = h * 8;
  int kh = wave & 1, qh = wave >> 1;
  int kw = kh * 32;                    // wave's key window within each 64-key chunk
  int qt = blockIdx.x;
  int bh = blockIdx.y;
  int b = bh / NHEAD, hd = bh % NHEAD;
  size_t base = (size_t)b * SEQ * QKV_N + hd * 192;

  const float kscale = 0.125f * 1.44269504088896f;  // scale * log2(e)

  // Q fragments (own q-half): B-operand col = q = qh*32 + l31, elem e <-> d = 16*ks + 8*h + e
  short8 qf[4];
  {
    const ushort_t* qp = qkv + base + (size_t)(qt * 64 + qh * 32 + l31) * QKV_N + h8;
    #pragma unroll
    for (int ks = 0; ks < 4; ++ks) qf[ks] = *(const short8*)(qp + ks * 16);
  }

  // staging (256 threads stage the whole 128-key superstep into 2 chunks):
  int krow = t >> 1, kcol = (t & 1) * 32;
  int kcb = krow >> 6, krl = krow & 63;
  int kp = t & 63, vdb = (t >> 6) * 16;
  int vcb = kp >> 5, kpl = kp & 31;
  short8 kr[4], va[2], vb[2];
  auto kv_load = [&](int sbase) {
    const ushort_t* gk = qkv + base + (size_t)(sbase + krow) * QKV_N + 64 + kcol;
    #pragma unroll
    for (int i = 0; i < 4; ++i) kr[i] = *(const short8*)(gk + i * 8);
    const ushort_t* gv = qkv + base + (size_t)(sbase + 2 * kp) * QKV_N + 128 + vdb;
    va[0] = *(const short8*)gv;           va[1] = *(const short8*)(gv + 8);
    vb[0] = *(const short8*)(gv + QKV_N); vb[1] = *(const short8*)(gv + QKV_N + 8);
  };
  auto kv_write = [&]() {
    #pragma unroll
    for (int i = 0; i < 4; ++i)
      *(short8*)&Ks[kcb][krl * 72 + kcol + i * 8] = kr[i];
    unsigned* vtw = (unsigned*)&Vt[vcb][0];
    #pragma unroll
    for (int half = 0; half < 2; ++half)
      #pragma unroll
      for (int e = 0; e < 8; ++e) {
        unsigned pk = (unsigned)(unsigned short)va[half][e] |
                      ((unsigned)(unsigned short)vb[half][e] << 16);
        vtw[(vdb + half * 8 + e) * 36 + kpl] = pk;   // Vt[d][keys 2kpl, 2kpl+1]
      }
  };

  f32x16 o0, o1;                 // O[q = qh*32 + (8g+4h+r)][d = l31 / 32+l31]
  #pragma unroll
  for (int i = 0; i < 16; ++i) { o0[i] = 0.f; o1[i] = 0.f; }
  float ls = 0.f;                // partial denominator for q = qh*32 + l31

  kv_load(0);
  for (int it = 0; it < SEQ / 128; ++it) {
    kv_write();
    __syncthreads();                       // superstep staged; prev reads done
    if (it + 1 < SEQ / 128) kv_load((it + 1) * 128);

    #pragma unroll
    for (int c = 0; c < 2; ++c) {          // the two 64-key chunks
      // ---- QK^T (swapped): S^T[key, q]
      f32x16 s;
      #pragma unroll
      for (int i = 0; i < 16; ++i) s[i] = 0.f;
      __builtin_amdgcn_s_setprio(1);
      #pragma unroll
      for (int ks = 0; ks < 4; ++ks) {
        short8 kf = *(const short8*)&Ks[c][(kw + l31) * 72 + ks * 16 + h8];
        s = __builtin_amdgcn_mfma_f32_32x32x16_bf16(kf, qf[ks], s, 0, 0, 0);
      }
      __builtin_amdgcn_s_setprio(0);

      // ---- softmax numerator (fixed max = 0); reg (4g+r) <-> window-key = 8g+4h+r
      unsigned wpk[4][2];
      #pragma unroll
      for (int g = 0; g < 4; ++g) {
        float p0 = exp2f(s[4 * g + 0] * kscale), p1 = exp2f(s[4 * g + 1] * kscale);
        float p2 = exp2f(s[4 * g + 2] * kscale), p3 = exp2f(s[4 * g + 3] * kscale);
        ls += (p0 + p1) + (p2 + p3);
        wpk[g][0] = cvtpk_bf16(p0, p1);
        wpk[g][1] = cvtpk_bf16(p2, p3);
      }

      // ---- PV: O += P * V over own 32-key window; A-frag via half-wave exchange
      #pragma unroll
      for (int k4 = 0; k4 < 2; ++k4) {
        int j2 = k4 * 2;
        unsigned f[4];
        #pragma unroll
        for (int c2 = 0; c2 < 2; ++c2) {
          unsigned a  = wpk[j2][c2];        // window-keys 16k4 + 4h + {2c2, 2c2+1}
          unsigned b2 = wpk[j2 + 1][c2];    // window-keys 16k4 + 8 + 4h + {2c2, 2c2+1}
          unsigned snd = h ? a : b2;
          unsigned rcv = (unsigned)__shfl_xor((int)snd, 32, 64);
          f[c2]     = h ? rcv : a;
          f[2 + c2] = h ? b2 : rcv;
        }
        union { unsigned u[4]; short8 s8; } uc;
        uc.u[0] = f[0]; uc.u[1] = f[1]; uc.u[2] = f[2]; uc.u[3] = f[3];
        short8 ap = uc.s8;
        short8 v0 = *(const short8*)&Vt[c][(l31)      * 72 + kw + k4 * 16 + h8];
        short8 v1 = *(const short8*)&Vt[c][(32 + l31) * 72 + kw + k4 * 16 + h8];
        __builtin_amdgcn_s_setprio(1);
        o0 = __builtin_amdgcn_mfma_f32_32x32x16_bf16(ap, v0, o0, 0, 0, 0);
        o1 = __builtin_amdgcn_mfma_f32_32x32x16_bf16(ap, v1, o1, 0, 0, 0);
        __builtin_amdgcn_s_setprio(0);
      }
    }
    __syncthreads();                       // all reads done before next superstep writes
  }

  // ---- combine key-halves: wave (1,qh) -> wave (0,qh); partials additive
  float* slab = (float*)&Ks[0][0];         // 128 lanes x 33 f = 16896B (fits in Ks)
  if (kh == 1) {
    float* s = slab + (size_t)(qh * 64 + lane) * 33;
    #pragma unroll
    for (int i = 0; i < 16; ++i) { s[i] = o0[i]; s[16 + i] = o1[i]; }
    s[32] = ls;
  }
  __syncthreads();
  if (kh == 0) {
    float* s = slab + (size_t)(qh * 64 + lane) * 33;
    #pragma unroll
    for (int i = 0; i < 16; ++i) { o0[i] += s[i]; o1[i] += s[16 + i]; }
    ls += s[32];
    // fold h-partner (each lane's ls covers only own-h window rows)
    ls += __shfl_xor(ls, 32, 64);

    // epilogue: rows q = qt*64 + qh*32 + (8g+4h+r); cols d = l31 / 32+l31
    size_t ob = (size_t)(b * SEQ + qt * 64 + qh * 32) * D_MODEL + hd * HDIM;
    #pragma unroll
    for (int g = 0; g < 4; ++g) {
      #pragma unroll
      for (int r = 0; r < 4; ++r) {
        int reg = 4 * g + r;
        int qrow = 8 * g + 4 * h + r;
        float inv = 1.0f / __shfl(ls, qrow, 64);
        ushort_t* orow = out + ob + (size_t)qrow * D_MODEL;
        orow[l31]      = f2b(o0[reg] * inv);
        orow[32 + l31] = f2b(o1[reg] * inv);
      }
    }
  }
}

// ---------------------------------------------------------------- launch
extern "C" void kernel_launch(void* const* d_in, const int* in_sizes, int n_in,
                              void* d_out, int out_size, void* d_ws, size_t ws_size,
                              hipStream_t stream) {
  const float* x_in  = (const float*)d_in[0];
  const float* qkv_w = (const float*)d_in[1];
  const float* qkv_b = (const float*)d_in[2];
  const float* out_w = (const float*)d_in[3];
  const float* out_b = (const float*)d_in[4];
  const float* ln1_w = (const float*)d_in[5];
  const float* ln1_b = (const float*)d_in[6];
  const float* fc1_w = (const float*)d_in[7];
  const float* fc1_b = (const float*)d_in[8];
  const float* fc2_w = (const float*)d_in[9];
  const float* fc2_b = (const float*)d_in[10];
  const float* ln2_w = (const float*)d_in[11];
  const float* ln2_b = (const float*)d_in[12];

  char* ws = (char*)d_ws;
  size_t off = 0;
  auto alloc = [&](size_t bytes) -> void* {
    void* p = ws + off; off += (bytes + 255) & ~(size_t)255; return p;
  };
  float*    buf_x  = (float*)   alloc((size_t)NTOK * D_MODEL * 4);
  float*    buf_x2 = (float*)   alloc((size_t)NTOK * D_MODEL * 4);
  ushort_t* bigb   = (ushort_t*)alloc((size_t)NTOK * D_FF * 2);     // qkv_a / mlp_b union
  ushort_t* h_b    = (ushort_t*)alloc((size_t)NTOK * D_MODEL * 2);
  ushort_t* at_b   = (ushort_t*)alloc((size_t)NTOK * D_MODEL * 2);

  size_t off_base = off;
  size_t pl_w = ((size_t)QKV_N * D_MODEL + (size_t)D_MODEL * D_MODEL +
                 (size_t)D_FF * D_MODEL * 2) * 2;                   // bytes/layer (transposed)
  size_t splitk_bytes = (size_t)4 * NTOK * D_MODEL * 4;             // 4 fp32 partials
  bool use_splitk, all_layers;
  size_t slack = 64 << 10;
  if (ws_size >= off_base + splitk_bytes + 4 * pl_w + slack)      { use_splitk = true;  all_layers = true;  }
  else if (ws_size >= off_base + splitk_bytes + pl_w + slack)     { use_splitk = true;  all_layers = false; }
  else if (ws_size >= off_base + 4 * pl_w + slack)                { use_splitk = false; all_layers = true;  }
  else                                                            { use_splitk = false; all_layers = false; }
  float* Pbuf = use_splitk ? (float*)alloc(splitk_bytes) : nullptr;
  int nl = all_layers ? 4 : 1;
  ushort_t* qkvT = (ushort_t*)alloc((size_t)QKV_N * D_MODEL * 2 * nl);
  ushort_t* outT = (ushort_t*)alloc((size_t)D_MODEL * D_MODEL * 2 * nl);
  ushort_t* f1T  = (ushort_t*)alloc((size_t)D_FF * D_MODEL * 2 * nl);
  ushort_t* f2T  = (ushort_t*)alloc((size_t)D_MODEL * D_FF * 2 * nl);

  ushort_t* qkv_a = bigb;
  ushort_t* mlp_b = bigb;

  if (all_layers)
    transpose_layers<<<dim3(6912, 4), dim3(32, 8), 0, stream>>>(
        qkv_w, out_w, fc1_w, fc2_w, qkvT, outT, f1T, f2T);

  for (int l = 0; l < 4; ++l) {
    const float* resid_in = (l == 0) ? x_in : buf_x;
    size_t lw = all_layers ? (size_t)l : 0;
    ushort_t* qkvT_l = qkvT + lw * QKV_N * D_MODEL;
    ushort_t* outT_l = outT + lw * D_MODEL * D_MODEL;
    ushort_t* f1T_l  = f1T  + lw * D_FF * D_MODEL;
    ushort_t* f2T_l  = f2T  + lw * D_MODEL * D_FF;
    if (!all_layers)
      transpose_layers<<<dim3(6912, 1), dim3(32, 8), 0, stream>>>(
          qkv_w + (size_t)l * D_MODEL * QKV_N, out_w + (size_t)l * D_MODEL * D_MODEL,
          fc1_w + (size_t)l * D_MODEL * D_FF,  fc2_w + (size_t)l * D_FF * D_MODEL,
          qkvT_l, outT_l, f1T_l, f2T_l);
    // ln1: layer 0 always; later layers only if combine_ln didn't already produce h_b
    if (l == 0 || !use_splitk)
      ln_kernel<<<NTOK, 256, 0, stream>>>(resid_in, ln1_w + l * D_MODEL, ln1_b + l * D_MODEL, h_b);
    gemm_kernel<0, 96><<<dim3(QKV_N / 96, NTOK / 128), 256, 0, stream>>>(
        h_b, qkvT_l, qkv_b + l * QKV_N, qkv_a, NTOK, QKV_N, D_MODEL);
    attn_kernel<<<dim3(SEQ / 64, 2 * NHEAD), 256, 0, stream>>>(qkv_a, at_b);
    gemm64_kernel<<<dim3(D_MODEL / 64, NTOK / 64), 256, 0, stream>>>(
        at_b, outT_l, out_b + l * D_MODEL, resid_in, buf_x2, NTOK, D_MODEL, D_MODEL);
    ln_kernel<<<NTOK, 256, 0, stream>>>(buf_x2, ln2_w + l * D_MODEL, ln2_b + l * D_MODEL, h_b);
    gemm_kernel<1, 128><<<dim3(D_FF / 128, NTOK / 128), 256, 0, stream>>>(
        h_b, f1T_l, fc1_b + l * D_FF, mlp_b, NTOK, D_FF, D_MODEL);
    if (use_splitk) {
      gemm_splitk_kernel<<<dim3(D_MODEL / 128, NTOK / 128, 4), 256, 0, stream>>>(
          mlp_b, f2T_l, Pbuf, NTOK, D_MODEL, D_FF, D_FF / 4);
      if (l < 3)
        combine_ln_kernel<1><<<NTOK, 256, 0, stream>>>(
            Pbuf, fc2_b + l * D_MODEL, buf_x2,
            ln1_w + (l + 1) * D_MODEL, ln1_b + (l + 1) * D_MODEL, buf_x, h_b);
      else
        combine_ln_kernel<0><<<NTOK, 256, 0, stream>>>(
            Pbuf, fc2_b + 3 * D_MODEL, buf_x2, nullptr, nullptr, (float*)d_out, nullptr);
    } else {
      float* x_next = (l < 3) ? buf_x : (float*)d_out;
      gemm64_kernel<<<dim3(D_MODEL / 64, NTOK / 64), 256, 0, stream>>>(
          mlp_b, f2T_l, fc2_b + l * D_MODEL, buf_x2, x_next, NTOK, D_MODEL, D_FF);
    }
  }
  (void)in_sizes; (void)n_in; (void)out_size;
}

// Round 15
// 881.413 us; speedup vs baseline: 1.0751x; 1.0095x over previous
//
#include <hip/hip_runtime.h>
#include <stdint.h>
#include <math.h>

// Problem constants
#define D_MODEL 768
#define NTOK    4096      // B*S = 2*2048
#define SEQ     2048
#define NHEAD   12
#define HDIM    64
#define D_FF    3072
#define QKV_N   2304      // 3*D_MODEL

typedef unsigned short ushort_t;  // raw bf16 bits
typedef short  short8 __attribute__((ext_vector_type(8)));
typedef float  f32x4  __attribute__((ext_vector_type(4)));
typedef float  f32x16 __attribute__((ext_vector_type(16)));

__device__ __forceinline__ float b2f(ushort_t u) {
  union { unsigned int u; float f; } v; v.u = ((unsigned int)u) << 16; return v.f;
}
__device__ __forceinline__ ushort_t f2b(float f) {
  union { float f; unsigned int u; } v; v.f = f;
  unsigned int u = v.u;
  return (ushort_t)((u + 0x7fffu + ((u >> 16) & 1u)) >> 16);  // RNE
}
__device__ __forceinline__ unsigned cvtpk_bf16(float lo, float hi) {
  unsigned r;
  asm("v_cvt_pk_bf16_f32 %0, %1, %2" : "=v"(r) : "v"(lo), "v"(hi));
  return r;
}

// ---------------------------------------------------------------- weight transpose+cast
// [K,N] fp32 -> [N,K] bf16. blockIdx.y = layer (grid.y=4 all-layer mode, 1 per-layer).
__global__ __launch_bounds__(256) void transpose_layers(
    const float* __restrict__ qkv_w, const float* __restrict__ out_w,
    const float* __restrict__ fc1_w, const float* __restrict__ fc2_w,
    ushort_t* __restrict__ qkvT, ushort_t* __restrict__ outT,
    ushort_t* __restrict__ f1T, ushort_t* __restrict__ f2T) {
  __shared__ ushort_t tile[32][33];
  int bid = blockIdx.x;
  size_t l = blockIdx.y;
  const float* src; ushort_t* dst; int K, N, tn, tk;
  if (bid < 1728)      { src = qkv_w + l * D_MODEL * QKV_N; dst = qkvT + l * D_MODEL * QKV_N;
                         K = 768;  N = 2304; tn = bid % 72;  tk = bid / 72; }
  else if (bid < 2304) { int b = bid - 1728; src = out_w + l * D_MODEL * D_MODEL; dst = outT + l * D_MODEL * D_MODEL;
                         K = 768;  N = 768;  tn = b % 24; tk = b / 24; }
  else if (bid < 4608) { int b = bid - 2304; src = fc1_w + l * D_MODEL * D_FF; dst = f1T + l * D_MODEL * D_FF;
                         K = 768;  N = 3072; tn = b % 96; tk = b / 96; }
  else                 { int b = bid - 4608; src = fc2_w + l * D_FF * D_MODEL; dst = f2T + l * D_FF * D_MODEL;
                         K = 3072; N = 768;  tn = b % 24; tk = b / 24; }
  int n0 = tn * 32, k0 = tk * 32;
  int tx = threadIdx.x, ty = threadIdx.y;       // (32,8)
  #pragma unroll
  for (int i = 0; i < 32; i += 8)
    tile[ty + i][tx] = f2b(src[(size_t)(k0 + ty + i) * N + n0 + tx]);
  __syncthreads();
  #pragma unroll
  for (int i = 0; i < 32; i += 8)
    dst[(size_t)(n0 + ty + i) * K + k0 + tx] = tile[tx][ty + i];
}

// ---------------------------------------------------------------- layernorm
__global__ __launch_bounds__(256) void ln_kernel(const float* __restrict__ x,
                                                 const float* __restrict__ w,
                                                 const float* __restrict__ b,
                                                 ushort_t* __restrict__ out) {
  __shared__ float red[4];
  int tok = blockIdx.x, t = threadIdx.x;
  const float* xr = x + (size_t)tok * D_MODEL;
  float v0 = xr[t], v1 = xr[t + 256], v2 = xr[t + 512];
  float s = v0 + v1 + v2;
  #pragma unroll
  for (int o = 1; o < 64; o <<= 1) s += __shfl_xor(s, o, 64);
  if ((t & 63) == 0) red[t >> 6] = s;
  __syncthreads();
  float mean = (red[0] + red[1] + red[2] + red[3]) * (1.0f / 768.0f);
  __syncthreads();
  float d0 = v0 - mean, d1 = v1 - mean, d2 = v2 - mean;
  float q = d0 * d0 + d1 * d1 + d2 * d2;
  #pragma unroll
  for (int o = 1; o < 64; o <<= 1) q += __shfl_xor(q, o, 64);
  if ((t & 63) == 0) red[t >> 6] = q;
  __syncthreads();
  float var = (red[0] + red[1] + red[2] + red[3]) * (1.0f / 768.0f);
  float rs = rsqrtf(var + 1e-5f);
  ushort_t* orow = out + (size_t)tok * D_MODEL;
  orow[t]       = f2b(d0 * rs * w[t]       + b[t]);
  orow[t + 256] = f2b(d1 * rs * w[t + 256] + b[t + 256]);
  orow[t + 512] = f2b(d2 * rs * w[t + 512] + b[t + 512]);
}

// ---------------------------------------------------------------- combine + (optional) layernorm
// x = sum of 4 split-K partials (bf16, r15) + bias + resid -> xout (fp32);
// DO_LN: also LN -> h bf16. Partial |values| ~0.3-3; bf16 quantization adds
// ~0.005-0.02 abs on x (damped by LN) — within the >=0.0625 absmax tolerance.
template <int DO_LN>
__global__ __launch_bounds__(256) void combine_ln_kernel(
    const ushort_t* __restrict__ P, const float* __restrict__ bias,
    const float* __restrict__ resid, const float* __restrict__ w,
    const float* __restrict__ b, float* __restrict__ xout,
    ushort_t* __restrict__ h) {
  __shared__ float red[4];
  int tok = blockIdx.x, t = threadIdx.x;
  size_t ro = (size_t)tok * D_MODEL;
  const size_t PS = (size_t)NTOK * D_MODEL;
  int c0 = t, c1 = t + 256, c2 = t + 512;
  float v0 = bias[c0] + resid[ro + c0] + b2f(P[ro + c0]) + b2f(P[PS + ro + c0])
           + b2f(P[2 * PS + ro + c0]) + b2f(P[3 * PS + ro + c0]);
  float v1 = bias[c1] + resid[ro + c1] + b2f(P[ro + c1]) + b2f(P[PS + ro + c1])
           + b2f(P[2 * PS + ro + c1]) + b2f(P[3 * PS + ro + c1]);
  float v2 = bias[c2] + resid[ro + c2] + b2f(P[ro + c2]) + b2f(P[PS + ro + c2])
           + b2f(P[2 * PS + ro + c2]) + b2f(P[3 * PS + ro + c2]);
  xout[ro + c0] = v0; xout[ro + c1] = v1; xout[ro + c2] = v2;
  if constexpr (DO_LN) {
    float s = v0 + v1 + v2;
    #pragma unroll
    for (int o = 1; o < 64; o <<= 1) s += __shfl_xor(s, o, 64);
    if ((t & 63) == 0) red[t >> 6] = s;
    __syncthreads();
    float mean = (red[0] + red[1] + red[2] + red[3]) * (1.0f / 768.0f);
    __syncthreads();
    float d0 = v0 - mean, d1 = v1 - mean, d2 = v2 - mean;
    float q = d0 * d0 + d1 * d1 + d2 * d2;
    #pragma unroll
    for (int o = 1; o < 64; o <<= 1) q += __shfl_xor(q, o, 64);
    if ((t & 63) == 0) red[t >> 6] = q;
    __syncthreads();
    float var = (red[0] + red[1] + red[2] + red[3]) * (1.0f / 768.0f);
    float rs = rsqrtf(var + 1e-5f);
    ushort_t* orow = h + ro;
    orow[c0] = f2b(d0 * rs * w[c0] + b[c0]);
    orow[c1] = f2b(d1 * rs * w[c1] + b[c1]);
    orow[c2] = f2b(d2 * rs * w[c2] + b[c2]);
  }
}

// ---------------------------------------------------------------- GEMM (MFMA bf16), 128 x TN tile
// C[M,N] = A[M,K] * BT[N,K]^T + bias. DOUBLE-BUFFERED K-loop, one barrier/iter.
// XCD-chunked block swizzle. EPI: 0 bias->bf16 | 1 bias+gelu->bf16
// TN=96 (qkv N=2304): grid 24x32 = 768 blocks = exactly 3/CU; wave = 64x48;
// B staged in 1.5 passes, wave-uniform-dest global_load_lds (r14: neutral).
template <int EPI, int TN>
__global__ __launch_bounds__(256) void gemm_kernel(
    const ushort_t* __restrict__ A, const ushort_t* __restrict__ BT,
    const float* __restrict__ bias,
    ushort_t* __restrict__ Cb, int M, int N, int K) {
  constexpr int NI = 4;
  constexpr int NJ = (TN == 96) ? 3 : 4;
  __shared__ ushort_t As[2][128 * 32];
  __shared__ ushort_t Bs[2][TN * 32];
  int t = threadIdx.x;
  int lane = t & 63, wave = t >> 6;
  // XCD-aware bijective chunk swizzle (T1)
  int gx = gridDim.x;
  int nwg = gx * gridDim.y;
  int bid0 = blockIdx.y * gx + blockIdx.x;
  int qn = nwg >> 3, rm = nwg & 7;
  int xcd = bid0 & 7, pos = bid0 >> 3;
  int wg = (xcd < rm ? xcd * (qn + 1) : rm * (qn + 1) + (xcd - rm) * qn) + pos;
  int m0 = (wg / gx) * 128, n0 = (wg % gx) * TN;
  int wm = (wave & 1) * 64;
  int wn = (wave >> 1) * (TN / 2);
  int quad = lane >> 4, l16 = lane & 15;
  int kq = quad * 8;
  int lrow = lane >> 2, lcol = (lane & 3) * 8;   // staging: 16B per lane

  auto gload = [&](const ushort_t* g, ushort_t* l) {
    __builtin_amdgcn_global_load_lds((const __attribute__((address_space(1))) void*)g,
                                     (__attribute__((address_space(3))) void*)l, 16, 0, 0);
  };

  auto stage = [&](int k0, int buf) {
    #pragma unroll
    for (int c = 0; c < 2; ++c) {
      int rowA = wave * 32 + c * 16 + lrow;
      gload(A + (size_t)(m0 + rowA) * K + k0 + lcol, &As[buf][(wave * 32 + c * 16) * 32]);
      if (TN == 128)
        gload(BT + (size_t)(n0 + rowA) * K + k0 + lcol, &Bs[buf][(wave * 32 + c * 16) * 32]);
    }
    if (TN == 96) {
      int rowB = wave * 16 + lrow;                 // rows 0..63: all 4 waves
      gload(BT + (size_t)(n0 + rowB) * K + k0 + lcol, &Bs[buf][(wave * 16) * 32]);
      if (wave < 2) {                              // rows 64..95: waves 0,1
        int rowB2 = 64 + wave * 16 + lrow;
        gload(BT + (size_t)(n0 + rowB2) * K + k0 + lcol, &Bs[buf][(64 + wave * 16) * 32]);
      }
    }
  };

  f32x4 acc[NI][NJ];
  #pragma unroll
  for (int i = 0; i < NI; ++i)
    #pragma unroll
    for (int j = 0; j < NJ; ++j) acc[i][j] = (f32x4){0.f, 0.f, 0.f, 0.f};

  stage(0, 0);                      // prologue prefetch
  int nk = K / 32;
  for (int ki = 0; ki < nk; ++ki) {
    int cur = ki & 1;
    __syncthreads();                // tile ki resident; prev reads of buf[cur^1] done
    if (ki + 1 < nk) stage((ki + 1) * 32, cur ^ 1);
    short8 af[NI], bf[NJ];
    #pragma unroll
    for (int i = 0; i < NI; ++i)
      af[i] = *(const short8*)&As[cur][(wm + i * 16 + l16) * 32 + kq];
    #pragma unroll
    for (int j = 0; j < NJ; ++j)
      bf[j] = *(const short8*)&Bs[cur][(wn + j * 16 + l16) * 32 + kq];
    #pragma unroll
    for (int i = 0; i < NI; ++i)
      #pragma unroll
      for (int j = 0; j < NJ; ++j)
        acc[i][j] = __builtin_amdgcn_mfma_f32_16x16x32_bf16(af[i], bf[j], acc[i][j], 0, 0, 0);
  }

  #pragma unroll
  for (int i = 0; i < NI; ++i) {
    #pragma unroll
    for (int j = 0; j < NJ; ++j) {
      int col = n0 + wn + j * 16 + l16;
      float bv = bias[col];
      #pragma unroll
      for (int r = 0; r < 4; ++r) {
        int row = m0 + wm + i * 16 + quad * 4 + r;
        float v = acc[i][j][r] + bv;
        if (EPI == 1) {
          // gelu tanh-form: v * e/(e+1), e = exp2(2.302208*(v + 0.044715 v^3))
          float u = v + 0.044715f * v * v * v;
          u = fminf(u, 30.0f);                    // avoid inf/inf
          float e = exp2f(2.302207848f * u);
          v = v * e / (e + 1.0f);
        }
        Cb[(size_t)row * N + col] = f2b(v);
      }
    }
  }
}

// ---------------------------------------------------------------- split-K GEMM (128x128 tile, bf16 partials)
// fc2 (M=4096, N=768, K=3072): split-K x4, grid (6,32,4) = 768 blocks = 3/CU
// at full 128^2 intensity. r15: partials stored bf16 (halves P round-trip
// traffic, 200MB/run); summed in fp32 by combine_ln_kernel.
__global__ __launch_bounds__(256) void gemm_splitk_kernel(
    const ushort_t* __restrict__ A, const ushort_t* __restrict__ BT,
    ushort_t* __restrict__ P, int M, int N, int K, int KS) {
  __shared__ ushort_t As[2][128 * 32];
  __shared__ ushort_t Bs[2][128 * 32];
  int t = threadIdx.x;
  int lane = t & 63, wave = t >> 6;
  int gx = gridDim.x;
  int nwg = gx * gridDim.y;              // per-slice block count (192: div by 8)
  int bid0 = blockIdx.y * gx + blockIdx.x;
  int qn = nwg >> 3, rm = nwg & 7;
  int xcd = bid0 & 7, pos = bid0 >> 3;
  int wg = (xcd < rm ? xcd * (qn + 1) : rm * (qn + 1) + (xcd - rm) * qn) + pos;
  int m0 = (wg / gx) * 128, n0 = (wg % gx) * 128;
  int kbase = blockIdx.z * KS;
  int wm = (wave & 1) * 64, wn = (wave >> 1) * 64;
  int quad = lane >> 4, l16 = lane & 15;
  int kq = quad * 8;
  int lrow = lane >> 2, lcol = (lane & 3) * 8;

  auto stage = [&](int k0, int buf) {
    #pragma unroll
    for (int c = 0; c < 2; ++c) {
      int rowA = wave * 32 + c * 16 + lrow;
      const ushort_t* ga = A + (size_t)(m0 + rowA) * K + kbase + k0 + lcol;
      ushort_t* la = &As[buf][(wave * 32 + c * 16) * 32];
      __builtin_amdgcn_global_load_lds((const __attribute__((address_space(1))) void*)ga,
                                       (__attribute__((address_space(3))) void*)la, 16, 0, 0);
      const ushort_t* gb = BT + (size_t)(n0 + rowA) * K + kbase + k0 + lcol;
      ushort_t* lb = &Bs[buf][(wave * 32 + c * 16) * 32];
      __builtin_amdgcn_global_load_lds((const __attribute__((address_space(1))) void*)gb,
                                       (__attribute__((address_space(3))) void*)lb, 16, 0, 0);
    }
  };

  f32x4 acc[4][4];
  #pragma unroll
  for (int i = 0; i < 4; ++i)
    #pragma unroll
    for (int j = 0; j < 4; ++j) acc[i][j] = (f32x4){0.f, 0.f, 0.f, 0.f};

  stage(0, 0);
  int nk = KS / 32;
  for (int ki = 0; ki < nk; ++ki) {
    int cur = ki & 1;
    __syncthreads();
    if (ki + 1 < nk) stage((ki + 1) * 32, cur ^ 1);
    short8 af[4], bf[4];
    #pragma unroll
    for (int i = 0; i < 4; ++i)
      af[i] = *(const short8*)&As[cur][(wm + i * 16 + l16) * 32 + kq];
    #pragma unroll
    for (int j = 0; j < 4; ++j)
      bf[j] = *(const short8*)&Bs[cur][(wn + j * 16 + l16) * 32 + kq];
    #pragma unroll
    for (int i = 0; i < 4; ++i)
      #pragma unroll
      for (int j = 0; j < 4; ++j)
        acc[i][j] = __builtin_amdgcn_mfma_f32_16x16x32_bf16(af[i], bf[j], acc[i][j], 0, 0, 0);
  }

  ushort_t* Pz = P + (size_t)blockIdx.z * M * N;
  #pragma unroll
  for (int i = 0; i < 4; ++i) {
    #pragma unroll
    for (int j = 0; j < 4; ++j) {
      int col = n0 + wn + j * 16 + l16;
      #pragma unroll
      for (int r = 0; r < 4; ++r) {
        int row = m0 + wm + i * 16 + quad * 4 + r;
        Pz[(size_t)row * N + col] = f2b(acc[i][j][r]);
      }
    }
  }
}

// ---------------------------------------------------------------- GEMM 64x64 tile (residual epilogue)
// For the out-proj GEMM: 64x64 tile, grid 768 = 3/CU. C = A*BT^T + bias + resid -> fp32.
__global__ __launch_bounds__(256) void gemm64_kernel(
    const ushort_t* __restrict__ A, const ushort_t* __restrict__ BT,
    const float* __restrict__ bias, const float* __restrict__ resid,
    float* __restrict__ Cf, int M, int N, int K) {
  __shared__ ushort_t As[2][64 * 32];
  __shared__ ushort_t Bs[2][64 * 32];
  int t = threadIdx.x;
  int lane = t & 63, wave = t >> 6;
  int gx = gridDim.x;
  int nwg = gx * gridDim.y;
  int bid0 = blockIdx.y * gx + blockIdx.x;
  int qn = nwg >> 3, rm = nwg & 7;
  int xcd = bid0 & 7, pos = bid0 >> 3;
  int wg = (xcd < rm ? xcd * (qn + 1) : rm * (qn + 1) + (xcd - rm) * qn) + pos;
  int m0 = (wg / gx) * 64, n0 = (wg % gx) * 64;
  int wm = (wave & 1) * 32, wn = (wave >> 1) * 32;
  int quad = lane >> 4, l16 = lane & 15;
  int kq = quad * 8;
  int lrow = lane >> 2, lcol = (lane & 3) * 8;   // 4 threads/row, 16B each

  auto stage = [&](int k0, int buf) {
    int row = wave * 16 + lrow;                  // 64 rows over 4 waves
    const ushort_t* ga = A + (size_t)(m0 + row) * K + k0 + lcol;
    ushort_t* la = &As[buf][(wave * 16) * 32];
    __builtin_amdgcn_global_load_lds((const __attribute__((address_space(1))) void*)ga,
                                     (__attribute__((address_space(3))) void*)la, 16, 0, 0);
    const ushort_t* gb = BT + (size_t)(n0 + row) * K + k0 + lcol;
    ushort_t* lb = &Bs[buf][(wave * 16) * 32];
    __builtin_amdgcn_global_load_lds((const __attribute__((address_space(1))) void*)gb,
                                     (__attribute__((address_space(3))) void*)lb, 16, 0, 0);
  };

  f32x4 acc[2][2];
  #pragma unroll
  for (int i = 0; i < 2; ++i)
    #pragma unroll
    for (int j = 0; j < 2; ++j) acc[i][j] = (f32x4){0.f, 0.f, 0.f, 0.f};

  stage(0, 0);
  int nk = K / 32;
  for (int ki = 0; ki < nk; ++ki) {
    int cur = ki & 1;
    __syncthreads();
    if (ki + 1 < nk) stage((ki + 1) * 32, cur ^ 1);
    short8 af[2], bf[2];
    #pragma unroll
    for (int i = 0; i < 2; ++i)
      af[i] = *(const short8*)&As[cur][(wm + i * 16 + l16) * 32 + kq];
    #pragma unroll
    for (int j = 0; j < 2; ++j)
      bf[j] = *(const short8*)&Bs[cur][(wn + j * 16 + l16) * 32 + kq];
    #pragma unroll
    for (int i = 0; i < 2; ++i)
      #pragma unroll
      for (int j = 0; j < 2; ++j)
        acc[i][j] = __builtin_amdgcn_mfma_f32_16x16x32_bf16(af[i], bf[j], acc[i][j], 0, 0, 0);
  }

  #pragma unroll
  for (int i = 0; i < 2; ++i) {
    #pragma unroll
    for (int j = 0; j < 2; ++j) {
      int col = n0 + wn + j * 16 + l16;
      float bv = bias[col];
      #pragma unroll
      for (int r = 0; r < 4; ++r) {
        int row = m0 + wm + i * 16 + quad * 4 + r;
        float v = acc[i][j][r] + bv + resid[(size_t)row * N + col];
        Cf[(size_t)row * N + col] = v;
      }
    }
  }
}

// ---------------------------------------------------------------- attention (MFMA 32x32, 2x2 wave partition)
// qkv bf16 [NTOK, 2304]; token t, head hd: [hd*192 + (q:0|k:64|v:128) + d]
// r4/r7/r9/r11/r13/r14-proven structure (63.0us, VGPR 68, zero conflicts).
// (256,3) is REQUIRED: grid 768 = exactly 3 blocks/CU (grid-capped), and any
// tighter VGPR cap spills (r12: (256,4) -> WRITE 6144->8448, 63.1->66.6us).
__global__ __launch_bounds__(256, 3) void attn_kernel(const ushort_t* __restrict__ qkv,
                                                      ushort_t* __restrict__ out) {
  __shared__ __align__(16) ushort_t Ks[2][64 * 72];   // [chunk][key][d], pad 72
  __shared__ __align__(16) ushort_t Vt[2][64 * 72];   // [chunk][d][key], pad 72
  int t = threadIdx.x;
  int lane = t & 63, wave = t >> 6;
  int l31 = lane & 31, h = lane >> 5, h8 = h * 8;
  int kh = wave & 1, qh = wave >> 1;
  int kw = kh * 32;                    // wave's key window within each 64-key chunk
  int qt = blockIdx.x;
  int bh = blockIdx.y;
  int b = bh / NHEAD, hd = bh % NHEAD;
  size_t base = (size_t)b * SEQ * QKV_N + hd * 192;

  const float kscale = 0.125f * 1.44269504088896f;  // scale * log2(e)

  // Q fragments (own q-half): B-operand col = q = qh*32 + l31, elem e <-> d = 16*ks + 8*h + e
  short8 qf[4];
  {
    const ushort_t* qp = qkv + base + (size_t)(qt * 64 + qh * 32 + l31) * QKV_N + h8;
    #pragma unroll
    for (int ks = 0; ks < 4; ++ks) qf[ks] = *(const short8*)(qp + ks * 16);
  }

  // staging (256 threads stage the whole 128-key superstep into 2 chunks):
  int krow = t >> 1, kcol = (t & 1) * 32;
  int kcb = krow >> 6, krl = krow & 63;
  int kp = t & 63, vdb = (t >> 6) * 16;
  int vcb = kp >> 5, kpl = kp & 31;
  short8 kr[4], va[2], vb[2];
  auto kv_load = [&](int sbase) {
    const ushort_t* gk = qkv + base + (size_t)(sbase + krow) * QKV_N + 64 + kcol;
    #pragma unroll
    for (int i = 0; i < 4; ++i) kr[i] = *(const short8*)(gk + i * 8);
    const ushort_t* gv = qkv + base + (size_t)(sbase + 2 * kp) * QKV_N + 128 + vdb;
    va[0] = *(const short8*)gv;           va[1] = *(const short8*)(gv + 8);
    vb[0] = *(const short8*)(gv + QKV_N); vb[1] = *(const short8*)(gv + QKV_N + 8);
  };
  auto kv_write = [&]() {
    #pragma unroll
    for (int i = 0; i < 4; ++i)
      *(short8*)&Ks[kcb][krl * 72 + kcol + i * 8] = kr[i];
    unsigned* vtw = (unsigned*)&Vt[vcb][0];
    #pragma unroll
    for (int half = 0; half < 2; ++half)
      #pragma unroll
      for (int e = 0; e < 8; ++e) {
        unsigned pk = (unsigned)(unsigned short)va[half][e] |
                      ((unsigned)(unsigned short)vb[half][e] << 16);
        vtw[(vdb + half * 8 + e) * 36 + kpl] = pk;   // Vt[d][keys 2kpl, 2kpl+1]
      }
  };

  f32x16 o0, o1;                 // O[q = qh*32 + (8g+4h+r)][d = l31 / 32+l31]
  #pragma unroll
  for (int i = 0; i < 16; ++i) { o0[i] = 0.f; o1[i] = 0.f; }
  float ls = 0.f;                // partial denominator for q = qh*32 + l31

  kv_load(0);
  for (int it = 0; it < SEQ / 128; ++it) {
    kv_write();
    __syncthreads();                       // superstep staged; prev reads done
    if (it + 1 < SEQ / 128) kv_load((it + 1) * 128);

    #pragma unroll
    for (int c = 0; c < 2; ++c) {          // the two 64-key chunks
      // ---- QK^T (swapped): S^T[key, q]
      f32x16 s;
      #pragma unroll
      for (int i = 0; i < 16; ++i) s[i] = 0.f;
      __builtin_amdgcn_s_setprio(1);
      #pragma unroll
      for (int ks = 0; ks < 4; ++ks) {
        short8 kf = *(const short8*)&Ks[c][(kw + l31) * 72 + ks * 16 + h8];
        s = __builtin_amdgcn_mfma_f32_32x32x16_bf16(kf, qf[ks], s, 0, 0, 0);
      }
      __builtin_amdgcn_s_setprio(0);

      // ---- softmax numerator (fixed max = 0); reg (4g+r) <-> window-key = 8g+4h+r
      unsigned wpk[4][2];
      #pragma unroll
      for (int g = 0; g < 4; ++g) {
        float p0 = exp2f(s[4 * g + 0] * kscale), p1 = exp2f(s[4 * g + 1] * kscale);
        float p2 = exp2f(s[4 * g + 2] * kscale), p3 = exp2f(s[4 * g + 3] * kscale);
        ls += (p0 + p1) + (p2 + p3);
        wpk[g][0] = cvtpk_bf16(p0, p1);
        wpk[g][1] = cvtpk_bf16(p2, p3);
      }

      // ---- PV: O += P * V over own 32-key window; A-frag via half-wave exchange
      #pragma unroll
      for (int k4 = 0; k4 < 2; ++k4) {
        int j2 = k4 * 2;
        unsigned f[4];
        #pragma unroll
        for (int c2 = 0; c2 < 2; ++c2) {
          unsigned a  = wpk[j2][c2];        // window-keys 16k4 + 4h + {2c2, 2c2+1}
          unsigned b2 = wpk[j2 + 1][c2];    // window-keys 16k4 + 8 + 4h + {2c2, 2c2+1}
          unsigned snd = h ? a : b2;
          unsigned rcv = (unsigned)__shfl_xor((int)snd, 32, 64);
          f[c2]     = h ? rcv : a;
          f[2 + c2] = h ? b2 : rcv;
        }
        union { unsigned u[4]; short8 s8; } uc;
        uc.u[0] = f[0]; uc.u[1] = f[1]; uc.u[2] = f[2]; uc.u[3] = f[3];
        short8 ap = uc.s8;
        short8 v0 = *(const short8*)&Vt[c][(l31)      * 72 + kw + k4 * 16 + h8];
        short8 v1 = *(const short8*)&Vt[c][(32 + l31) * 72 + kw + k4 * 16 + h8];
        __builtin_amdgcn_s_setprio(1);
        o0 = __builtin_amdgcn_mfma_f32_32x32x16_bf16(ap, v0, o0, 0, 0, 0);
        o1 = __builtin_amdgcn_mfma_f32_32x32x16_bf16(ap, v1, o1, 0, 0, 0);
        __builtin_amdgcn_s_setprio(0);
      }
    }
    __syncthreads();                       // all reads done before next superstep writes
  }

  // ---- combine key-halves: wave (1,qh) -> wave (0,qh); partials additive
  float* slab = (float*)&Ks[0][0];         // 128 lanes x 33 f = 16896B (fits in Ks)
  if (kh == 1) {
    float* s = slab + (size_t)(qh * 64 + lane) * 33;
    #pragma unroll
    for (int i = 0; i < 16; ++i) { s[i] = o0[i]; s[16 + i] = o1[i]; }
    s[32] = ls;
  }
  __syncthreads();
  if (kh == 0) {
    float* s = slab + (size_t)(qh * 64 + lane) * 33;
    #pragma unroll
    for (int i = 0; i < 16; ++i) { o0[i] += s[i]; o1[i] += s[16 + i]; }
    ls += s[32];
    // fold h-partner (each lane's ls covers only own-h window rows)
    ls += __shfl_xor(ls, 32, 64);

    // epilogue: rows q = qt*64 + qh*32 + (8g+4h+r); cols d = l31 / 32+l31
    size_t ob = (size_t)(b * SEQ + qt * 64 + qh * 32) * D_MODEL + hd * HDIM;
    #pragma unroll
    for (int g = 0; g < 4; ++g) {
      #pragma unroll
      for (int r = 0; r < 4; ++r) {
        int reg = 4 * g + r;
        int qrow = 8 * g + 4 * h + r;
        float inv = 1.0f / __shfl(ls, qrow, 64);
        ushort_t* orow = out + ob + (size_t)qrow * D_MODEL;
        orow[l31]      = f2b(o0[reg] * inv);
        orow[32 + l31] = f2b(o1[reg] * inv);
      }
    }
  }
}

// ---------------------------------------------------------------- launch
extern "C" void kernel_launch(void* const* d_in, const int* in_sizes, int n_in,
                              void* d_out, int out_size, void* d_ws, size_t ws_size,
                              hipStream_t stream) {
  const float* x_in  = (const float*)d_in[0];
  const float* qkv_w = (const float*)d_in[1];
  const float* qkv_b = (const float*)d_in[2];
  const float* out_w = (const float*)d_in[3];
  const float* out_b = (const float*)d_in[4];
  const float* ln1_w = (const float*)d_in[5];
  const float* ln1_b = (const float*)d_in[6];
  const float* fc1_w = (const float*)d_in[7];
  const float* fc1_b = (const float*)d_in[8];
  const float* fc2_w = (const float*)d_in[9];
  const float* fc2_b = (const float*)d_in[10];
  const float* ln2_w = (const float*)d_in[11];
  const float* ln2_b = (const float*)d_in[12];

  char* ws = (char*)d_ws;
  size_t off = 0;
  auto alloc = [&](size_t bytes) -> void* {
    void* p = ws + off; off += (bytes + 255) & ~(size_t)255; return p;
  };
  float*    buf_x  = (float*)   alloc((size_t)NTOK * D_MODEL * 4);
  float*    buf_x2 = (float*)   alloc((size_t)NTOK * D_MODEL * 4);
  ushort_t* bigb   = (ushort_t*)alloc((size_t)NTOK * D_FF * 2);     // qkv_a / mlp_b union
  ushort_t* h_b    = (ushort_t*)alloc((size_t)NTOK * D_MODEL * 2);
  ushort_t* at_b   = (ushort_t*)alloc((size_t)NTOK * D_MODEL * 2);

  size_t off_base = off;
  size_t pl_w = ((size_t)QKV_N * D_MODEL + (size_t)D_MODEL * D_MODEL +
                 (size_t)D_FF * D_MODEL * 2) * 2;                   // bytes/layer (transposed)
  size_t splitk_bytes = (size_t)4 * NTOK * D_MODEL * 2;             // 4 bf16 partials (r15)
  bool use_splitk, all_layers;
  size_t slack = 64 << 10;
  if (ws_size >= off_base + splitk_bytes + 4 * pl_w + slack)      { use_splitk = true;  all_layers = true;  }
  else if (ws_size >= off_base + splitk_bytes + pl_w + slack)     { use_splitk = true;  all_layers = false; }
  else if (ws_size >= off_base + 4 * pl_w + slack)                { use_splitk = false; all_layers = true;  }
  else                                                            { use_splitk = false; all_layers = false; }
  ushort_t* Pbuf = use_splitk ? (ushort_t*)alloc(splitk_bytes) : nullptr;
  int nl = all_layers ? 4 : 1;
  ushort_t* qkvT = (ushort_t*)alloc((size_t)QKV_N * D_MODEL * 2 * nl);
  ushort_t* outT = (ushort_t*)alloc((size_t)D_MODEL * D_MODEL * 2 * nl);
  ushort_t* f1T  = (ushort_t*)alloc((size_t)D_FF * D_MODEL * 2 * nl);
  ushort_t* f2T  = (ushort_t*)alloc((size_t)D_MODEL * D_FF * 2 * nl);

  ushort_t* qkv_a = bigb;
  ushort_t* mlp_b = bigb;

  if (all_layers)
    transpose_layers<<<dim3(6912, 4), dim3(32, 8), 0, stream>>>(
        qkv_w, out_w, fc1_w, fc2_w, qkvT, outT, f1T, f2T);

  for (int l = 0; l < 4; ++l) {
    const float* resid_in = (l == 0) ? x_in : buf_x;
    size_t lw = all_layers ? (size_t)l : 0;
    ushort_t* qkvT_l = qkvT + lw * QKV_N * D_MODEL;
    ushort_t* outT_l = outT + lw * D_MODEL * D_MODEL;
    ushort_t* f1T_l  = f1T  + lw * D_FF * D_MODEL;
    ushort_t* f2T_l  = f2T  + lw * D_MODEL * D_FF;
    if (!all_layers)
      transpose_layers<<<dim3(6912, 1), dim3(32, 8), 0, stream>>>(
          qkv_w + (size_t)l * D_MODEL * QKV_N, out_w + (size_t)l * D_MODEL * D_MODEL,
          fc1_w + (size_t)l * D_MODEL * D_FF,  fc2_w + (size_t)l * D_FF * D_MODEL,
          qkvT_l, outT_l, f1T_l, f2T_l);
    // ln1: layer 0 always; later layers only if combine_ln didn't already produce h_b
    if (l == 0 || !use_splitk)
      ln_kernel<<<NTOK, 256, 0, stream>>>(resid_in, ln1_w + l * D_MODEL, ln1_b + l * D_MODEL, h_b);
    gemm_kernel<0, 96><<<dim3(QKV_N / 96, NTOK / 128), 256, 0, stream>>>(
        h_b, qkvT_l, qkv_b + l * QKV_N, qkv_a, NTOK, QKV_N, D_MODEL);
    attn_kernel<<<dim3(SEQ / 64, 2 * NHEAD), 256, 0, stream>>>(qkv_a, at_b);
    gemm64_kernel<<<dim3(D_MODEL / 64, NTOK / 64), 256, 0, stream>>>(
        at_b, outT_l, out_b + l * D_MODEL, resid_in, buf_x2, NTOK, D_MODEL, D_MODEL);
    ln_kernel<<<NTOK, 256, 0, stream>>>(buf_x2, ln2_w + l * D_MODEL, ln2_b + l * D_MODEL, h_b);
    gemm_kernel<1, 128><<<dim3(D_FF / 128, NTOK / 128), 256, 0, stream>>>(
        h_b, f1T_l, fc1_b + l * D_FF, mlp_b, NTOK, D_FF, D_MODEL);
    if (use_splitk) {
      gemm_splitk_kernel<<<dim3(D_MODEL / 128, NTOK / 128, 4), 256, 0, stream>>>(
          mlp_b, f2T_l, Pbuf, NTOK, D_MODEL, D_FF, D_FF / 4);
      if (l < 3)
        combine_ln_kernel<1><<<NTOK, 256, 0, stream>>>(
            Pbuf, fc2_b + l * D_MODEL, buf_x2,
            ln1_w + (l + 1) * D_MODEL, ln1_b + (l + 1) * D_MODEL, buf_x, h_b);
      else
        combine_ln_kernel<0><<<NTOK, 256, 0, stream>>>(
            Pbuf, fc2_b + 3 * D_MODEL, buf_x2, nullptr, nullptr, (float*)d_out, nullptr);
    } else {
      float* x_next = (l < 3) ? buf_x : (float*)d_out;
      gemm64_kernel<<<dim3(D_MODEL / 64, NTOK / 64), 256, 0, stream>>>(
          mlp_b, f2T_l, fc2_b + l * D_MODEL, buf_x2, x_next, NTOK, D_MODEL, D_FF);
    }
  }
  (void)in_sizes; (void)n_in; (void)out_size;
}